// Round 13
// baseline (1213.383 us; speedup 1.0000x reference)
//
#include <hip/hip_runtime.h>
#include <hip/hip_bf16.h>
#include <stdint.h>

#define BB 256
#define CC 1024
#define NP 25
#define EPS 1e-5f

typedef __attribute__((ext_vector_type(8))) short bf16x8;
typedef __attribute__((ext_vector_type(4))) float f32x4;
typedef unsigned int u32;

#define MFMA16(A, B, C) __builtin_amdgcn_mfma_f32_16x16x32_bf16(A, B, C, 0, 0, 0)

// async global->LDS, 16B per lane; LDS dest = wave-uniform base + lane*16
__device__ __forceinline__ void gload16(const u32* g, u32* l)
{
  __builtin_amdgcn_global_load_lds(
      (const __attribute__((address_space(1))) u32*)g,
      (__attribute__((address_space(3))) u32*)l, 16, 0, 0);
}

// ---------------------------------------------------------------- utils

__device__ __forceinline__ void head_entry(int j, int* pp, int* ww)
{
  int cnt = 0;
  for (int y1 = 0; y1 < 5; y1++)
    for (int x1 = 0; x1 < 5; x1++) {
      int p = y1 * 5 + x1;
      int y2 = y1 + 2, x2 = x1 + 2;
      if (y2 == 2 || y2 == 3)
        for (int s = 0; s < 3; s++) { if (y2 + s + 1 > 6) break; if (cnt == j) { *pp = p; *ww = 0 + s; return; } cnt++; }
      if (y1 == 3 || y1 == 4)
        for (int s = 0; s < 3; s++) { if (y1 - (s + 1) < 0) break; if (cnt == j) { *pp = p; *ww = 3 + s; return; } cnt++; }
      if (x2 == 2 || x2 == 3)
        for (int s = 0; s < 3; s++) { if (x2 + s + 1 > 6) break; if (cnt == j) { *pp = p; *ww = 6 + s; return; } cnt++; }
      if (x1 == 3 || x1 == 4)
        for (int s = 0; s < 3; s++) { if (x1 - (s + 1) < 0) break; if (cnt == j) { *pp = p; *ww = 9 + s; return; } cnt++; }
    }
}

// split fp32 -> hi bf16 (truncate) + lo bf16 (remainder); pack pairs into u32
__device__ __forceinline__ void split_f4(float4 f, uint2& h, uint2& l)
{
  u32 ux = __float_as_uint(f.x), uy = __float_as_uint(f.y);
  u32 uz = __float_as_uint(f.z), uw = __float_as_uint(f.w);
  h.x = (ux >> 16) | (uy & 0xFFFF0000u);
  h.y = (uz >> 16) | (uw & 0xFFFF0000u);
  float lx = f.x - __uint_as_float(ux & 0xFFFF0000u);
  float ly = f.y - __uint_as_float(uy & 0xFFFF0000u);
  float lz = f.z - __uint_as_float(uz & 0xFFFF0000u);
  float lw = f.w - __uint_as_float(uw & 0xFFFF0000u);
  l.x = (__float_as_uint(lx) >> 16) | (__float_as_uint(ly) & 0xFFFF0000u);
  l.y = (__float_as_uint(lz) >> 16) | (__float_as_uint(lw) & 0xFFFF0000u);
}

// round-to-nearest-even bf16 (keep high 16 bits)
__device__ __forceinline__ u32 rne_hi(u32 x)
{
  return (x + 0x7FFFu + ((x >> 16) & 1u)) & 0xFFFF0000u;
}

// ------------------------------------------------- layer-1 stats from x

__global__ void k_xsums(const float* __restrict__ x, float* __restrict__ xs1,
                        float* __restrict__ xs2)
{
  int pos = blockIdx.x * 256 + threadIdx.x;   // < 50176
  float s1 = 0.f, s2 = 0.f;
  for (int b = 0; b < BB; b++) {
    float v = x[(size_t)b * 50176 + pos];
    s1 += v; s2 = fmaf(v, v, s2);
  }
  xs1[pos] = s1; xs2[pos] = s2;
}

__global__ void k_stats1(const float* __restrict__ xs1, const float* __restrict__ xs2,
                         const float* __restrict__ gam, const float* __restrict__ bet,
                         float* __restrict__ ssc, float* __restrict__ ssh)
{
  int p = blockIdx.x;
  int c = blockIdx.y * 256 + threadIdx.x;
  int y1 = p / 5, x1 = p % 5;
  float s1 = 0.f, s2 = 0.f;
  for (int dy = 0; dy < 3; dy++)
    for (int dx = 0; dx < 3; dx++) {
      int pos = c * 49 + (y1 + dy) * 7 + (x1 + dx);
      s1 += xs1[pos]; s2 += xs2[pos];
    }
  const float inv = 1.0f / 2304.0f;
  float mean = s1 * inv;
  float var  = s2 * inv - mean * mean;
  float rs   = rsqrtf(var + EPS);
  float sc   = rs * gam[c];
  ssc[(size_t)p * CC + c] = sc;
  ssh[(size_t)p * CC + c] = bet[c] - mean * sc;
}

// ------------------------- one-time x transpose: x[b][c][yx] -> xt[b][yx][c]

__global__ void k_transpose(const float* __restrict__ x, float* __restrict__ xt)
{
  __shared__ float tile[128][51];
  int b = blockIdx.x, cg = blockIdx.y;
  const float* src = x + (size_t)b * 50176 + (size_t)cg * 128 * 49;
  for (int idx = threadIdx.x; idx < 6272; idx += 256)
    tile[idx / 49][idx % 49] = src[idx];
  __syncthreads();
  float* dst = xt + (size_t)b * 49 * 1024 + cg * 128;
  for (int pp = 0; pp < 50; pp += 2) {
    int p = pp + (threadIdx.x >> 7);
    int i = threadIdx.x & 127;
    if (p < 49) dst[(size_t)p * 1024 + i] = tile[i][p];
  }
}

// ---------- head weights / ctx pre-split (trunc hi+lo, 1024-u32 rows)
// row = 1024 u32: [slab 0..31][ 16 u32 hi pairs | 16 u32 lo pairs ]

__global__ void k_wsplit(const float* __restrict__ w, u32* __restrict__ dst, int total)
{
  int g = blockIdx.x * 256 + threadIdx.x;
  if (g >= total) return;
  int row = g >> 10;
  int rem = g & 1023;
  int slab = rem >> 5, j = rem & 31;
  int lo = j >> 4, jj = j & 15;
  const float* src = w + ((size_t)row << 10) + slab * 32 + 2 * jj;
  float f0 = src[0], f1 = src[1];
  u32 u0 = __float_as_uint(f0), u1 = __float_as_uint(f1);
  u32 v;
  if (lo == 0) {
    v = (u0 >> 16) | (u1 & 0xFFFF0000u);
  } else {
    float l0 = f0 - __uint_as_float(u0 & 0xFFFF0000u);
    float l1 = f1 - __uint_as_float(u1 & 0xFFFF0000u);
    v = (__float_as_uint(l0) >> 16) | (__float_as_uint(l1) & 0xFFFF0000u);
  }
  dst[g] = v;
}

// ---------- conv weights: RNE hi-only layout (512-u32 rows, slab = 16 u32)

__global__ void k_wsplit_rn(const float* __restrict__ w, u32* __restrict__ dst, int total)
{
  int g = blockIdx.x * 256 + threadIdx.x;
  if (g >= total) return;
  int row = g >> 9;
  int idx = g & 511;
  const float* src = w + ((size_t)row << 10) + 2 * idx;
  u32 u0 = __float_as_uint(src[0]);
  u32 u1 = __float_as_uint(src[1]);
  dst[g] = (rne_hi(u0) >> 16) | rne_hi(u1);
}

// ------------- A-operand affine+relu+split into gload layout (trunc hi+lo)
// MODE 0: src = fp32 rows (conv2 A); MODE 1: src = xt, patch row-map (conv1 A);
// MODE 2: src = x, strided reads (no-xt fallback).

template<int MODE>
__global__ void k_absplit(const float* __restrict__ src,
                          const float* __restrict__ ssc, const float* __restrict__ ssh,
                          u32* __restrict__ dst, int pbase)
{
  int r = blockIdx.x * 8 + (threadIdx.x >> 5);   // local row
  int slab = threadIdx.x & 31;
  int pg;
  const float* sp = nullptr;
  const float* xb = nullptr;
  if (MODE == 0) {
    pg = pbase + r / 2304;
    sp = src + (size_t)r * 1024 + slab * 32;
  } else {
    int pl = r / 2304, q = r - pl * 2304;
    pg = pbase + pl;
    int b = q / 9, yx = q - b * 9;
    int pos = (pg / 5 + yx / 3) * 7 + (pg % 5) + (yx % 3);
    if (MODE == 1) sp = src + ((size_t)b * 49 + pos) * 1024 + slab * 32;
    else           xb = src + (size_t)b * 50176 + (size_t)slab * 32 * 49 + pos;
  }
  const float* scp = ssc + (size_t)pg * CC + slab * 32;
  const float* shp = ssh + (size_t)pg * CC + slab * 32;
  u32 hi[16], lo[16];
  #pragma unroll
  for (int j = 0; j < 8; j++) {
    float4 f;
    if (MODE == 2) {
      f.x = xb[(size_t)(4 * j + 0) * 49]; f.y = xb[(size_t)(4 * j + 1) * 49];
      f.z = xb[(size_t)(4 * j + 2) * 49]; f.w = xb[(size_t)(4 * j + 3) * 49];
    } else {
      f = *(const float4*)(sp + 4 * j);
    }
    float4 s = *(const float4*)(scp + 4 * j);
    float4 h = *(const float4*)(shp + 4 * j);
    f.x = fmaxf(fmaf(f.x, s.x, h.x), 0.f);
    f.y = fmaxf(fmaf(f.y, s.y, h.y), 0.f);
    f.z = fmaxf(fmaf(f.z, s.z, h.z), 0.f);
    f.w = fmaxf(fmaf(f.w, s.w, h.w), 0.f);
    uint2 hh, ll;
    split_f4(f, hh, ll);
    hi[2 * j] = hh.x; hi[2 * j + 1] = hh.y;
    lo[2 * j] = ll.x; lo[2 * j + 1] = ll.y;
  }
  u32* op = dst + (size_t)r * 1024 + slab * 32;
  *(uint4*)(op + 0)  = make_uint4(hi[0], hi[1], hi[2], hi[3]);
  *(uint4*)(op + 4)  = make_uint4(hi[4], hi[5], hi[6], hi[7]);
  *(uint4*)(op + 8)  = make_uint4(hi[8], hi[9], hi[10], hi[11]);
  *(uint4*)(op + 12) = make_uint4(hi[12], hi[13], hi[14], hi[15]);
  *(uint4*)(op + 16) = make_uint4(lo[0], lo[1], lo[2], lo[3]);
  *(uint4*)(op + 20) = make_uint4(lo[4], lo[5], lo[6], lo[7]);
  *(uint4*)(op + 24) = make_uint4(lo[8], lo[9], lo[10], lo[11]);
  *(uint4*)(op + 28) = make_uint4(lo[12], lo[13], lo[14], lo[15]);
}

// ------------------- finalize BN stats from per-mblock partials (18/patch)

__global__ void k_statsfin(const float* __restrict__ part, const float* __restrict__ gam,
                           const float* __restrict__ bet, float* __restrict__ ssc,
                           float* __restrict__ ssh, int pbase)
{
  int pl = blockIdx.x;
  int c  = blockIdx.y * 256 + threadIdx.x;
  float s1 = 0.f, s2 = 0.f;
  for (int mb = 0; mb < 18; mb++) {
    const float* pp = part + ((size_t)(pl * 18 + mb) * CC + c) * 2;
    s1 += pp[0]; s2 += pp[1];
  }
  const float inv = 1.0f / 2304.0f;
  float mean = s1 * inv;
  float var  = s2 * inv - mean * mean;
  float rs   = rsqrtf(var + EPS);
  float sc   = rs * gam[c];
  int pg = pbase + pl;
  ssc[(size_t)pg * CC + c] = sc;
  ssh[(size_t)pg * CC + c] = bet[c] - mean * sc;
}

// ---- BN3 affine+relu + 3x3 mean pooling, output in split gload layout

__global__ void k_pool(const float* __restrict__ h, const float* __restrict__ ssc,
                       const float* __restrict__ ssh, u32* __restrict__ apool, int pbase)
{
  int row = blockIdx.x;                 // local: pl*256 + b
  int pl = row >> 8;
  int pg = pbase + pl;
  int c = threadIdx.x * 4;
  float4 sc = *(const float4*)(ssc + (size_t)pg * CC + c);
  float4 sh = *(const float4*)(ssh + (size_t)pg * CC + c);
  const float* hp = h + (size_t)row * 9 * CC + c;
  float4 s = {0.f, 0.f, 0.f, 0.f};
  #pragma unroll
  for (int yx = 0; yx < 9; yx++) {
    float4 v = *(const float4*)(hp + (size_t)yx * CC);
    s.x += fmaxf(fmaf(v.x, sc.x, sh.x), 0.f);
    s.y += fmaxf(fmaf(v.y, sc.y, sh.y), 0.f);
    s.z += fmaxf(fmaf(v.z, sc.z, sh.z), 0.f);
    s.w += fmaxf(fmaf(v.w, sc.w, sh.w), 0.f);
  }
  const float inv9 = 1.0f / 9.0f;
  float4 o = { s.x * inv9, s.y * inv9, s.z * inv9, s.w * inv9 };
  uint2 hh, ll;
  split_f4(o, hh, ll);
  int s_ = c >> 5, jj = (c & 31) >> 1;
  u32* op = apool + ((size_t)(pbase * 256) + row) * 1024 + s_ * 32;
  *(uint2*)(op + jj)      = hh;
  *(uint2*)(op + 16 + jj) = ll;
}

// ------------------------------------------------------------ MFMA GEMM core
// C[m][n] = sum_k A[m][k] * B[n][k] + bias[n]; A pre-split hi/lo, staged via
// global_load_lds. BP=2 (heads): B 2-plane trunc, 3 products. BP=1 (convs):
// B hi-only RNE (512-u32 rows), 2 products (ah+al)*bh.
// NJ = j-frags per wave; tile = 128 x (NJ*32).  conv NJ=8 -> 64 MFMA/slab.
// LDS: A row 32 u32, granule g^(row&7); B(BP=1) row 16 u32, granule
//   g^((row>>1)&3) (spreads same-parity rows over all 4 slots -> 2-way max).
// STATS: per-block column sum/sumsq -> partOut[mb][col][2].

template<int BP, bool STATS, int NJ>
__device__ __forceinline__ void mg_body(
    const u32* __restrict__ Agl, const u32* __restrict__ Bp,
    const float* __restrict__ bias, float* __restrict__ Cmat,
    int m0, int n0, float* __restrict__ partOut, int mb)
{
  constexpr int BRS   = (BP == 1) ? 512 : 1024;  // B global row stride (u32)
  constexpr int BLROW = (BP == 1) ? 16 : 32;     // B LDS row (u32)
  constexpr int BLDS  = NJ * 32 * BLROW;         // B LDS u32 per buffer
  __shared__ u32 sA[2][4096];
  __shared__ u32 sB[2][BLDS];
  __shared__ float sr1[4][NJ * 16];
  __shared__ float sr2[4][NJ * 16];

  const int t = threadIdx.x;
  const int l = t & 63, wv = t >> 6;
  const int lr = l & 15, lk = l >> 4;
  const int wm = (wv >> 1) * 64, wn = (wv & 1) * (NJ * 16);

  // fragment read offsets (u32) with granule XOR swizzle
  int fAh[4], fAl[4], fBh[NJ], fBl[NJ];
  #pragma unroll
  for (int i = 0; i < 4; i++) {
    int Ra = wm + i * 16 + lr;
    fAh[i] = Ra * 32 + ((lk ^ (Ra & 7)) << 2);
    fAl[i] = Ra * 32 + (((4 + lk) ^ (Ra & 7)) << 2);
  }
  #pragma unroll
  for (int j = 0; j < NJ; j++) {
    int Rb = wn + j * 16 + lr;
    if (BP == 1) {
      fBh[j] = Rb * 16 + ((lk ^ ((Rb >> 1) & 3)) << 2);
      fBl[j] = 0;
    } else {
      fBh[j] = Rb * 32 + ((lk ^ (Rb & 7)) << 2);
      fBl[j] = Rb * 32 + (((4 + lk) ^ (Rb & 7)) << 2);
    }
  }

  // A gload: 4 chunks of 8 rows (32-u32 rows)
  int growq[4], ggq[4];
  #pragma unroll
  for (int q = 0; q < 4; q++) {
    int rr = wv * 32 + q * 8 + (l >> 3);
    growq[q] = rr;
    ggq[q] = (((l & 7) ^ (rr & 7)) << 2);
  }
  // B gload: wave covers NJ*8 rows. BP=1: 16 rows/gload; BP=2: 8 rows/gload.
  constexpr int NBQ = (BP == 1) ? (NJ / 2) : NJ;
  int brow[NBQ], bg[NBQ], bdst[NBQ];
  #pragma unroll
  for (int q = 0; q < NBQ; q++) {
    if (BP == 1) {
      int rr = wv * (NJ * 8) + q * 16 + (l >> 2);
      brow[q] = rr;
      bg[q] = (((l & 3) ^ ((rr >> 1) & 3)) << 2);
      bdst[q] = (wv * (NJ * 8) + q * 16) * 16;
    } else {
      int rr = wv * (NJ * 8) + q * 8 + (l >> 3);
      brow[q] = rr;
      bg[q] = (((l & 7) ^ (rr & 7)) << 2);
      bdst[q] = (wv * (NJ * 8) + q * 8) * 32;
    }
  }
  const u32* Brow = Bp + (size_t)n0 * BRS;
  const u32* Agr  = Agl + (size_t)m0 * 1024;

  f32x4 acc[4][NJ];
  #pragma unroll
  for (int i = 0; i < 4; i++)
    #pragma unroll
    for (int j = 0; j < NJ; j++) { f32x4 z = {0.f, 0.f, 0.f, 0.f}; acc[i][j] = z; }

  // prologue: stage slab 0
  #pragma unroll
  for (int q = 0; q < NBQ; q++)
    gload16(Brow + (size_t)brow[q] * BRS + bg[q], &sB[0][bdst[q]]);
  #pragma unroll
  for (int q = 0; q < 4; q++)
    gload16(Agr + (size_t)growq[q] * 1024 + ggq[q],
            &sA[0][(wv * 32 + q * 8) * 32]);
  __syncthreads();

  #pragma unroll 1
  for (int it = 0; it < 32; ++it) {
    const int cur = it & 1, nxt = cur ^ 1;
    const bool pf = (it < 31);
    if (pf) {
      const int soA = (it + 1) << 5;
      const int soB = (BP == 1) ? ((it + 1) << 4) : soA;
      #pragma unroll
      for (int q = 0; q < NBQ; q++)
        gload16(Brow + (size_t)brow[q] * BRS + soB + bg[q], &sB[nxt][bdst[q]]);
      #pragma unroll
      for (int q = 0; q < 4; q++)
        gload16(Agr + (size_t)growq[q] * 1024 + soA + ggq[q],
                &sA[nxt][(wv * 32 + q * 8) * 32]);
    }
    bf16x8 Ah[4], Al_[4], Bh[NJ], Bl[NJ];
    #pragma unroll
    for (int i = 0; i < 4; i++) {
      Ah[i]  = *(const bf16x8*)&sA[cur][fAh[i]];
      Al_[i] = *(const bf16x8*)&sA[cur][fAl[i]];
    }
    #pragma unroll
    for (int j = 0; j < NJ; j++) {
      Bh[j] = *(const bf16x8*)&sB[cur][fBh[j]];
      if (BP == 2) Bl[j] = *(const bf16x8*)&sB[cur][fBl[j]];
    }
    #pragma unroll
    for (int i = 0; i < 4; i++)
      #pragma unroll
      for (int j = 0; j < NJ; j++) {
        acc[i][j] = MFMA16(Ah[i],  Bh[j], acc[i][j]);
        acc[i][j] = MFMA16(Al_[i], Bh[j], acc[i][j]);
        if (BP == 2) acc[i][j] = MFMA16(Ah[i], Bl[j], acc[i][j]);
      }
    __syncthreads();
  }

  // epilogue: D row = lk*4 + reg, col = lr [m89 layout]; optional col stats
  float st1[NJ], st2[NJ];
  #pragma unroll
  for (int j = 0; j < NJ; j++) { st1[j] = 0.f; st2[j] = 0.f; }
  #pragma unroll
  for (int j = 0; j < NJ; j++) {
    int ocol = n0 + wn + j * 16 + lr;
    float bj = bias[ocol];
    #pragma unroll
    for (int i = 0; i < 4; i++) {
      int orow = m0 + wm + i * 16 + lk * 4;
      float* cp = Cmat + (size_t)orow * CC + ocol;
      #pragma unroll
      for (int reg = 0; reg < 4; reg++) {
        float v = acc[i][j][reg] + bj;
        cp[(size_t)reg * CC] = v;
        if (STATS) { st1[j] += v; st2[j] = fmaf(v, v, st2[j]); }
      }
    }
  }
  if (STATS) {
    #pragma unroll
    for (int j = 0; j < NJ; j++) {
      st1[j] += __shfl_xor(st1[j], 16, 64);
      st1[j] += __shfl_xor(st1[j], 32, 64);
      st2[j] += __shfl_xor(st2[j], 16, 64);
      st2[j] += __shfl_xor(st2[j], 32, 64);
    }
    if (lk == 0) {
      #pragma unroll
      for (int j = 0; j < NJ; j++) {
        sr1[wv][j * 16 + lr] = st1[j];
        sr2[wv][j * 16 + lr] = st2[j];
      }
    }
    __syncthreads();
    if (t < NJ * 32) {
      int ch = t / (NJ * 16), c6 = t % (NJ * 16);
      float a1 = sr1[ch][c6] + sr1[ch + 2][c6];
      float a2 = sr2[ch][c6] + sr2[ch + 2][c6];
      float2 o = { a1, a2 };
      *(float2*)(partOut + ((size_t)mb * CC + n0 + t) * 2) = o;
    }
  }
}

// conv wrapper: 128x256 tile, 4 n-tiles; grouped swizzle (SWZ_G m-tiles/group)
#define SWZ_G 64

template<bool STATS>
__global__ __launch_bounds__(256, 2)
void k_mg(const u32* __restrict__ A, const u32* __restrict__ Bp,
          const float* __restrict__ bias, float* __restrict__ Cmat,
          int mtiles, float* __restrict__ partOut)
{
  int id = blockIdx.y * gridDim.x + blockIdx.x;
  int g = id / (SWZ_G * 4);
  int rem = id - g * (SWZ_G * 4);
  int gsz = mtiles - g * SWZ_G; if (gsz > SWZ_G) gsz = SWZ_G;
  int mt = g * SWZ_G + rem % gsz;
  int nt = rem / gsz;
  mg_body<1, STATS, 8>(A, Bp, bias, Cmat, mt * 128, nt * 256, partOut, mt);
}

__global__ __launch_bounds__(256, 2)
void k_heads(const u32* __restrict__ ctxp, const u32* __restrict__ wplh,
             const float* __restrict__ lb, float* __restrict__ out)
{
  int p, w;
  head_entry(blockIdx.y, &p, &w);
  mg_body<2, false, 4>(ctxp + (size_t)p * BB * 1024,
                       wplh + (size_t)w * 1048576,
                       lb + (size_t)w * CC,
                       out + (size_t)blockIdx.y * BB * CC,
                       (blockIdx.x >> 3) * 128, (blockIdx.x & 7) * 128,
                       nullptr, 0);
}

// ---------------------------------------------------------------- launch

extern "C" void kernel_launch(void* const* d_in, const int* in_sizes, int n_in,
                              void* d_out, int out_size, void* d_ws, size_t ws_size,
                              hipStream_t stream)
{
  const float* x   = (const float*)d_in[0];
  const float* bng = (const float*)d_in[1];
  const float* bnb = (const float*)d_in[2];
  const float* cw  = (const float*)d_in[3];
  const float* cb  = (const float*)d_in[4];
  const float* lw  = (const float*)d_in[5];
  const float* lb  = (const float*)d_in[6];
  float* out = (float*)d_out;
  float* ws  = (float*)d_ws;

  const size_t W = ws_size / 4;           // 4-byte words
  const size_t SZ_WHI  = 3ull * 524288;   // conv weights, RNE hi-only
  const size_t SZ_WPL  = 12ull * 1048576; // head weights, trunc hi+lo
  const size_t SZ_XT   = 256ull * 49 * 1024;
  const size_t SZ_PS   = 6400ull * 1024;  // pooled split (u32)
  const size_t SZ_CTX  = 6400ull * 1024;
  const size_t SZ_CTXP = 6400ull * 1024;
  const size_t SZ_XS   = 50176;
  const size_t SZ_SS   = 25ull * 1024;

  auto need = [&](int pc, bool xt) -> size_t {
    return SZ_WHI + SZ_WPL + (xt ? SZ_XT : 0) + 2ull * pc * 2304 * 1024
         + SZ_PS + SZ_CTX + SZ_CTXP + 2 * SZ_XS + 2 * SZ_SS
         + (size_t)pc * 18 * 1024 * 2;
  };
  int PC; bool useXT;
  if      (W >= need(25, true))  { PC = 25; useXT = true;  }
  else if (W >= need(5, true))   { PC = 5;  useXT = true;  }
  else if (W >= need(1, true))   { PC = 1;  useXT = true;  }
  else                           { PC = 1;  useXT = false; }

  u32*   whi    = (u32*)ws;
  u32*   wpl    = whi + SZ_WHI;
  float* xtg    = (float*)(wpl + SZ_WPL);
  float* bufF   = xtg + (useXT ? SZ_XT : 0);
  u32*   bufS   = (u32*)(bufF + (size_t)PC * 2304 * 1024);
  u32*   pooledS= bufS + (size_t)PC * 2304 * 1024;
  float* ctx    = (float*)(pooledS + SZ_PS);
  u32*   ctxp   = (u32*)(ctx + SZ_CTX);
  float* xs1    = (float*)(ctxp + SZ_CTXP);
  float* xs2    = xs1 + SZ_XS;
  float* ssc    = xs2 + SZ_XS;
  float* ssh    = ssc + SZ_SS;
  float* part   = ssh + SZ_SS;

  // weight pre-split: conv (RNE hi-only) + heads (trunc hi+lo)
  k_wsplit_rn<<<(int)(SZ_WHI / 256), 256, 0, stream>>>(cw, whi, (int)SZ_WHI);
  k_wsplit<<<(12 * 1048576) / 256, 256, 0, stream>>>(lw, wpl, 12 * 1048576);
  if (useXT) k_transpose<<<dim3(256, 8), 256, 0, stream>>>(x, xtg);
  k_xsums<<<196, 256, 0, stream>>>(x, xs1, xs2);
  k_stats1<<<dim3(25, 4), 256, 0, stream>>>(xs1, xs2, bng, bnb, ssc, ssh);

  for (int pbase = 0; pbase < NP; pbase += PC) {
    const int rows = PC * 2304;
    const int mtiles = PC * 18;
    const dim3 gconv(mtiles, 4);
    // A1: BN1+relu+split from xt (or x fallback) -> bufS
    if (useXT)
      k_absplit<1><<<rows / 8, 256, 0, stream>>>(xtg, ssc, ssh, bufS, pbase);
    else
      k_absplit<2><<<rows / 8, 256, 0, stream>>>(x, ssc, ssh, bufS, pbase);
    // conv1: bufS -> bufF, col stats -> part
    k_mg<true><<<gconv, 256, 0, stream>>>(bufS, whi, cb, bufF, mtiles, part);
    k_statsfin<<<dim3(PC, 4), 256, 0, stream>>>(part, bng + CC, bnb + CC, ssc, ssh, pbase);
    // A2: BN2+relu+split from bufF -> bufS
    k_absplit<0><<<rows / 8, 256, 0, stream>>>(bufF, ssc, ssh, bufS, pbase);
    // conv2: bufS -> bufF, stats -> part
    k_mg<true><<<gconv, 256, 0, stream>>>(bufS, whi + 524288, cb + CC,
                                          bufF, mtiles, part);
    k_statsfin<<<dim3(PC, 4), 256, 0, stream>>>(part, bng + 2 * CC, bnb + 2 * CC, ssc, ssh, pbase);
    // BN3+relu+pool, split output -> pooledS slice
    k_pool<<<PC * 256, 256, 0, stream>>>(bufF, ssc, ssh, pooledS, pbase);
  }

  // conv3 over all pooled rows -> ctx
  k_mg<false><<<dim3(50, 4), 256, 0, stream>>>(pooledS, whi + 2 * 524288,
                                               cb + 2 * CC, ctx, 50, nullptr);
  // ctx -> split (trunc hi+lo), then heads (3-product path)
  k_wsplit<<<(6400 * 1024) / 256, 256, 0, stream>>>(ctx, ctxp, 6400 * 1024);
  k_heads<<<dim3(16, 120), 256, 0, stream>>>(ctxp, wpl, lb, out);
}

// Round 14
// 932.966 us; speedup vs baseline: 1.3006x; 1.3006x over previous
//
#include <hip/hip_runtime.h>
#include <hip/hip_bf16.h>
#include <stdint.h>

#define BB 256
#define CC 1024
#define NP 25
#define EPS 1e-5f

typedef __attribute__((ext_vector_type(8))) short bf16x8;
typedef __attribute__((ext_vector_type(4))) float f32x4;
typedef unsigned int u32;

#define MFMA16(A, B, C) __builtin_amdgcn_mfma_f32_16x16x32_bf16(A, B, C, 0, 0, 0)

// async global->LDS, 16B per lane; LDS dest = wave-uniform base + lane*16
__device__ __forceinline__ void gload16(const u32* g, u32* l)
{
  __builtin_amdgcn_global_load_lds(
      (const __attribute__((address_space(1))) u32*)g,
      (__attribute__((address_space(3))) u32*)l, 16, 0, 0);
}

// ---------------------------------------------------------------- utils

__device__ __forceinline__ void head_entry(int j, int* pp, int* ww)
{
  int cnt = 0;
  for (int y1 = 0; y1 < 5; y1++)
    for (int x1 = 0; x1 < 5; x1++) {
      int p = y1 * 5 + x1;
      int y2 = y1 + 2, x2 = x1 + 2;
      if (y2 == 2 || y2 == 3)
        for (int s = 0; s < 3; s++) { if (y2 + s + 1 > 6) break; if (cnt == j) { *pp = p; *ww = 0 + s; return; } cnt++; }
      if (y1 == 3 || y1 == 4)
        for (int s = 0; s < 3; s++) { if (y1 - (s + 1) < 0) break; if (cnt == j) { *pp = p; *ww = 3 + s; return; } cnt++; }
      if (x2 == 2 || x2 == 3)
        for (int s = 0; s < 3; s++) { if (x2 + s + 1 > 6) break; if (cnt == j) { *pp = p; *ww = 6 + s; return; } cnt++; }
      if (x1 == 3 || x1 == 4)
        for (int s = 0; s < 3; s++) { if (x1 - (s + 1) < 0) break; if (cnt == j) { *pp = p; *ww = 9 + s; return; } cnt++; }
    }
}

// split fp32 -> hi bf16 (truncate) + lo bf16 (remainder); pack pairs into u32
__device__ __forceinline__ void split_f4(float4 f, uint2& h, uint2& l)
{
  u32 ux = __float_as_uint(f.x), uy = __float_as_uint(f.y);
  u32 uz = __float_as_uint(f.z), uw = __float_as_uint(f.w);
  h.x = (ux >> 16) | (uy & 0xFFFF0000u);
  h.y = (uz >> 16) | (uw & 0xFFFF0000u);
  float lx = f.x - __uint_as_float(ux & 0xFFFF0000u);
  float ly = f.y - __uint_as_float(uy & 0xFFFF0000u);
  float lz = f.z - __uint_as_float(uz & 0xFFFF0000u);
  float lw = f.w - __uint_as_float(uw & 0xFFFF0000u);
  l.x = (__float_as_uint(lx) >> 16) | (__float_as_uint(ly) & 0xFFFF0000u);
  l.y = (__float_as_uint(lz) >> 16) | (__float_as_uint(lw) & 0xFFFF0000u);
}

// round-to-nearest-even bf16 (keep high 16 bits)
__device__ __forceinline__ u32 rne_hi(u32 x)
{
  return (x + 0x7FFFu + ((x >> 16) & 1u)) & 0xFFFF0000u;
}

// pack two floats as RNE bf16 pair into one u32
__device__ __forceinline__ u32 rne_pack(float a, float b)
{
  return (rne_hi(__float_as_uint(a)) >> 16) | rne_hi(__float_as_uint(b));
}

// ------------------------------------------------- layer-1 stats from x

__global__ void k_xsums(const float* __restrict__ x, float* __restrict__ xs1,
                        float* __restrict__ xs2)
{
  int pos = blockIdx.x * 256 + threadIdx.x;   // < 50176
  float s1 = 0.f, s2 = 0.f;
  for (int b = 0; b < BB; b++) {
    float v = x[(size_t)b * 50176 + pos];
    s1 += v; s2 = fmaf(v, v, s2);
  }
  xs1[pos] = s1; xs2[pos] = s2;
}

__global__ void k_stats1(const float* __restrict__ xs1, const float* __restrict__ xs2,
                         const float* __restrict__ gam, const float* __restrict__ bet,
                         float* __restrict__ ssc, float* __restrict__ ssh)
{
  int p = blockIdx.x;
  int c = blockIdx.y * 256 + threadIdx.x;
  int y1 = p / 5, x1 = p % 5;
  float s1 = 0.f, s2 = 0.f;
  for (int dy = 0; dy < 3; dy++)
    for (int dx = 0; dx < 3; dx++) {
      int pos = c * 49 + (y1 + dy) * 7 + (x1 + dx);
      s1 += xs1[pos]; s2 += xs2[pos];
    }
  const float inv = 1.0f / 2304.0f;
  float mean = s1 * inv;
  float var  = s2 * inv - mean * mean;
  float rs   = rsqrtf(var + EPS);
  float sc   = rs * gam[c];
  ssc[(size_t)p * CC + c] = sc;
  ssh[(size_t)p * CC + c] = bet[c] - mean * sc;
}

// ------------------------- one-time x transpose: x[b][c][yx] -> xt[b][yx][c]

__global__ void k_transpose(const float* __restrict__ x, float* __restrict__ xt)
{
  __shared__ float tile[128][51];
  int b = blockIdx.x, cg = blockIdx.y;
  const float* src = x + (size_t)b * 50176 + (size_t)cg * 128 * 49;
  for (int idx = threadIdx.x; idx < 6272; idx += 256)
    tile[idx / 49][idx % 49] = src[idx];
  __syncthreads();
  float* dst = xt + (size_t)b * 49 * 1024 + cg * 128;
  for (int pp = 0; pp < 50; pp += 2) {
    int p = pp + (threadIdx.x >> 7);
    int i = threadIdx.x & 127;
    if (p < 49) dst[(size_t)p * 1024 + i] = tile[i][p];
  }
}

// ---------- head weights / ctx pre-split (trunc hi+lo, 1024-u32 rows)
// row = 1024 u32: [slab 0..31][ 16 u32 hi pairs | 16 u32 lo pairs ]

__global__ void k_wsplit(const float* __restrict__ w, u32* __restrict__ dst, int total)
{
  int g = blockIdx.x * 256 + threadIdx.x;
  if (g >= total) return;
  int row = g >> 10;
  int rem = g & 1023;
  int slab = rem >> 5, j = rem & 31;
  int lo = j >> 4, jj = j & 15;
  const float* src = w + ((size_t)row << 10) + slab * 32 + 2 * jj;
  float f0 = src[0], f1 = src[1];
  u32 u0 = __float_as_uint(f0), u1 = __float_as_uint(f1);
  u32 v;
  if (lo == 0) {
    v = (u0 >> 16) | (u1 & 0xFFFF0000u);
  } else {
    float l0 = f0 - __uint_as_float(u0 & 0xFFFF0000u);
    float l1 = f1 - __uint_as_float(u1 & 0xFFFF0000u);
    v = (__float_as_uint(l0) >> 16) | (__float_as_uint(l1) & 0xFFFF0000u);
  }
  dst[g] = v;
}

// ---------- conv weights: RNE hi-only layout (512-u32 rows, slab = 16 u32)

__global__ void k_wsplit_rn(const float* __restrict__ w, u32* __restrict__ dst, int total)
{
  int g = blockIdx.x * 256 + threadIdx.x;
  if (g >= total) return;
  int row = g >> 9;
  int idx = g & 511;
  const float* src = w + ((size_t)row << 10) + 2 * idx;
  dst[g] = rne_pack(src[0], src[1]);
}

// ------------- A-operand affine+relu+RNE into hi-only gload layout (512-u32 rows)
// MODE 0: src = fp32 rows (conv2 A); MODE 1: src = xt, patch row-map (conv1 A);
// MODE 2: src = x, strided reads (no-xt fallback).

template<int MODE>
__global__ void k_absplit(const float* __restrict__ src,
                          const float* __restrict__ ssc, const float* __restrict__ ssh,
                          u32* __restrict__ dst, int pbase)
{
  int r = blockIdx.x * 8 + (threadIdx.x >> 5);   // local row
  int slab = threadIdx.x & 31;
  int pg;
  const float* sp = nullptr;
  const float* xb = nullptr;
  if (MODE == 0) {
    pg = pbase + r / 2304;
    sp = src + (size_t)r * 1024 + slab * 32;
  } else {
    int pl = r / 2304, q = r - pl * 2304;
    pg = pbase + pl;
    int b = q / 9, yx = q - b * 9;
    int pos = (pg / 5 + yx / 3) * 7 + (pg % 5) + (yx % 3);
    if (MODE == 1) sp = src + ((size_t)b * 49 + pos) * 1024 + slab * 32;
    else           xb = src + (size_t)b * 50176 + (size_t)slab * 32 * 49 + pos;
  }
  const float* scp = ssc + (size_t)pg * CC + slab * 32;
  const float* shp = ssh + (size_t)pg * CC + slab * 32;
  u32 hi[16];
  #pragma unroll
  for (int j = 0; j < 8; j++) {
    float4 f;
    if (MODE == 2) {
      f.x = xb[(size_t)(4 * j + 0) * 49]; f.y = xb[(size_t)(4 * j + 1) * 49];
      f.z = xb[(size_t)(4 * j + 2) * 49]; f.w = xb[(size_t)(4 * j + 3) * 49];
    } else {
      f = *(const float4*)(sp + 4 * j);
    }
    float4 s = *(const float4*)(scp + 4 * j);
    float4 h = *(const float4*)(shp + 4 * j);
    f.x = fmaxf(fmaf(f.x, s.x, h.x), 0.f);
    f.y = fmaxf(fmaf(f.y, s.y, h.y), 0.f);
    f.z = fmaxf(fmaf(f.z, s.z, h.z), 0.f);
    f.w = fmaxf(fmaf(f.w, s.w, h.w), 0.f);
    hi[2 * j]     = rne_pack(f.x, f.y);
    hi[2 * j + 1] = rne_pack(f.z, f.w);
  }
  u32* op = dst + (size_t)r * 512 + slab * 16;
  *(uint4*)(op + 0)  = make_uint4(hi[0], hi[1], hi[2], hi[3]);
  *(uint4*)(op + 4)  = make_uint4(hi[4], hi[5], hi[6], hi[7]);
  *(uint4*)(op + 8)  = make_uint4(hi[8], hi[9], hi[10], hi[11]);
  *(uint4*)(op + 12) = make_uint4(hi[12], hi[13], hi[14], hi[15]);
}

// ------------------- finalize BN stats from per-mblock partials (18/patch)

__global__ void k_statsfin(const float* __restrict__ part, const float* __restrict__ gam,
                           const float* __restrict__ bet, float* __restrict__ ssc,
                           float* __restrict__ ssh, int pbase)
{
  int pl = blockIdx.x;
  int c  = blockIdx.y * 256 + threadIdx.x;
  float s1 = 0.f, s2 = 0.f;
  for (int mb = 0; mb < 18; mb++) {
    const float* pp = part + ((size_t)(pl * 18 + mb) * CC + c) * 2;
    s1 += pp[0]; s2 += pp[1];
  }
  const float inv = 1.0f / 2304.0f;
  float mean = s1 * inv;
  float var  = s2 * inv - mean * mean;
  float rs   = rsqrtf(var + EPS);
  float sc   = rs * gam[c];
  int pg = pbase + pl;
  ssc[(size_t)pg * CC + c] = sc;
  ssh[(size_t)pg * CC + c] = bet[c] - mean * sc;
}

// ---- BN3 affine+relu + 3x3 mean pooling, output RNE hi-only (512-u32 rows)

__global__ void k_pool(const float* __restrict__ h, const float* __restrict__ ssc,
                       const float* __restrict__ ssh, u32* __restrict__ apool, int pbase)
{
  int row = blockIdx.x;                 // local: pl*256 + b
  int pl = row >> 8;
  int pg = pbase + pl;
  int c = threadIdx.x * 4;
  float4 sc = *(const float4*)(ssc + (size_t)pg * CC + c);
  float4 sh = *(const float4*)(ssh + (size_t)pg * CC + c);
  const float* hp = h + (size_t)row * 9 * CC + c;
  float4 s = {0.f, 0.f, 0.f, 0.f};
  #pragma unroll
  for (int yx = 0; yx < 9; yx++) {
    float4 v = *(const float4*)(hp + (size_t)yx * CC);
    s.x += fmaxf(fmaf(v.x, sc.x, sh.x), 0.f);
    s.y += fmaxf(fmaf(v.y, sc.y, sh.y), 0.f);
    s.z += fmaxf(fmaf(v.z, sc.z, sh.z), 0.f);
    s.w += fmaxf(fmaf(v.w, sc.w, sh.w), 0.f);
  }
  const float inv9 = 1.0f / 9.0f;
  uint2 o = { rne_pack(s.x * inv9, s.y * inv9), rne_pack(s.z * inv9, s.w * inv9) };
  u32* op = apool + ((size_t)(pbase * 256) + row) * 512 + (c >> 1);
  *(uint2*)op = o;
}

// ------------------------------------------------------------ MFMA GEMM core
// C[m][n] = sum_k A[m][k] * B[n][k] + bias[n]; staged via global_load_lds.
// PREC=1 (convs): A,B both RNE hi-only (512-u32 rows), 1 product a*b.
// PREC=2 (heads): A,B both trunc hi/lo (1024-u32 rows), 3 products.
// LDS rows: PREC1 16 u32, granule g^((row>>1)&3) (2-way max);
//           PREC2 32 u32, granule g^(row&7).
// STATS: per-block column sum/sumsq -> partOut[mb][col][2].

template<int PREC, bool STATS>
__device__ __forceinline__ void mg_body(
    const u32* __restrict__ Agl, const u32* __restrict__ Bp,
    const float* __restrict__ bias, float* __restrict__ Cmat,
    int m0, int n0, float* __restrict__ partOut, int mb)
{
  constexpr int RS   = (PREC == 1) ? 512 : 1024;  // global row stride (u32)
  constexpr int LROW = (PREC == 1) ? 16 : 32;     // LDS row (u32)
  constexpr int LSZ  = 128 * LROW;                // LDS u32 per buffer
  __shared__ u32 sA[2][LSZ];
  __shared__ u32 sB[2][LSZ];
  __shared__ float sr1[4][64];
  __shared__ float sr2[4][64];

  const int t = threadIdx.x;
  const int l = t & 63, wv = t >> 6;
  const int lr = l & 15, lk = l >> 4;
  const int wm = (wv >> 1) * 64, wn = (wv & 1) * 64;

  // fragment read offsets (u32) with granule XOR swizzle
  int fAh[4], fAl[4], fBh[4], fBl[4];
  #pragma unroll
  for (int i = 0; i < 4; i++) {
    int Ra = wm + i * 16 + lr;
    int Rb = wn + i * 16 + lr;
    if (PREC == 1) {
      fAh[i] = Ra * 16 + ((lk ^ ((Ra >> 1) & 3)) << 2);
      fBh[i] = Rb * 16 + ((lk ^ ((Rb >> 1) & 3)) << 2);
      fAl[i] = 0; fBl[i] = 0;
    } else {
      fAh[i] = Ra * 32 + ((lk ^ (Ra & 7)) << 2);
      fAl[i] = Ra * 32 + (((4 + lk) ^ (Ra & 7)) << 2);
      fBh[i] = Rb * 32 + ((lk ^ (Rb & 7)) << 2);
      fBl[i] = Rb * 32 + (((4 + lk) ^ (Rb & 7)) << 2);
    }
  }

  // gload addressing: PREC1 -> 2 chunks of 16 rows; PREC2 -> 4 chunks of 8 rows
  constexpr int NQ = (PREC == 1) ? 2 : 4;
  int grow[NQ], gg[NQ], gdst[NQ];
  #pragma unroll
  for (int q = 0; q < NQ; q++) {
    if (PREC == 1) {
      int rr = wv * 32 + q * 16 + (l >> 2);
      grow[q] = rr;
      gg[q] = (((l & 3) ^ ((rr >> 1) & 3)) << 2);
      gdst[q] = (wv * 32 + q * 16) * 16;
    } else {
      int rr = wv * 32 + q * 8 + (l >> 3);
      grow[q] = rr;
      gg[q] = (((l & 7) ^ (rr & 7)) << 2);
      gdst[q] = (wv * 32 + q * 8) * 32;
    }
  }
  const u32* Brow = Bp + (size_t)n0 * RS;
  const u32* Agr  = Agl + (size_t)m0 * RS;

  f32x4 acc[4][4];
  #pragma unroll
  for (int i = 0; i < 4; i++)
    #pragma unroll
    for (int j = 0; j < 4; j++) { f32x4 z = {0.f, 0.f, 0.f, 0.f}; acc[i][j] = z; }

  // prologue: stage slab 0
  #pragma unroll
  for (int q = 0; q < NQ; q++) {
    gload16(Brow + (size_t)grow[q] * RS + gg[q], &sB[0][gdst[q]]);
    gload16(Agr + (size_t)grow[q] * RS + gg[q], &sA[0][gdst[q]]);
  }
  __syncthreads();

  #pragma unroll 1
  for (int it = 0; it < 32; ++it) {
    const int cur = it & 1, nxt = cur ^ 1;
    const bool pf = (it < 31);
    if (pf) {
      const int so = (PREC == 1) ? ((it + 1) << 4) : ((it + 1) << 5);
      #pragma unroll
      for (int q = 0; q < NQ; q++) {
        gload16(Brow + (size_t)grow[q] * RS + so + gg[q], &sB[nxt][gdst[q]]);
        gload16(Agr + (size_t)grow[q] * RS + so + gg[q], &sA[nxt][gdst[q]]);
      }
    }
    bf16x8 Ah[4], Al_[4], Bh[4], Bl[4];
    #pragma unroll
    for (int i = 0; i < 4; i++) {
      Ah[i] = *(const bf16x8*)&sA[cur][fAh[i]];
      Bh[i] = *(const bf16x8*)&sB[cur][fBh[i]];
      if (PREC == 2) {
        Al_[i] = *(const bf16x8*)&sA[cur][fAl[i]];
        Bl[i]  = *(const bf16x8*)&sB[cur][fBl[i]];
      }
    }
    #pragma unroll
    for (int i = 0; i < 4; i++)
      #pragma unroll
      for (int j = 0; j < 4; j++) {
        acc[i][j] = MFMA16(Ah[i], Bh[j], acc[i][j]);
        if (PREC == 2) {
          acc[i][j] = MFMA16(Al_[i], Bh[j], acc[i][j]);
          acc[i][j] = MFMA16(Ah[i],  Bl[j], acc[i][j]);
        }
      }
    __syncthreads();
  }

  // epilogue: D row = lk*4 + reg, col = lr [m89 layout]; optional col stats
  float st1[4], st2[4];
  #pragma unroll
  for (int j = 0; j < 4; j++) { st1[j] = 0.f; st2[j] = 0.f; }
  #pragma unroll
  for (int j = 0; j < 4; j++) {
    int ocol = n0 + wn + j * 16 + lr;
    float bj = bias[ocol];
    #pragma unroll
    for (int i = 0; i < 4; i++) {
      int orow = m0 + wm + i * 16 + lk * 4;
      float* cp = Cmat + (size_t)orow * CC + ocol;
      #pragma unroll
      for (int reg = 0; reg < 4; reg++) {
        float v = acc[i][j][reg] + bj;
        cp[(size_t)reg * CC] = v;
        if (STATS) { st1[j] += v; st2[j] = fmaf(v, v, st2[j]); }
      }
    }
  }
  if (STATS) {
    #pragma unroll
    for (int j = 0; j < 4; j++) {
      st1[j] += __shfl_xor(st1[j], 16, 64);
      st1[j] += __shfl_xor(st1[j], 32, 64);
      st2[j] += __shfl_xor(st2[j], 16, 64);
      st2[j] += __shfl_xor(st2[j], 32, 64);
    }
    if (lk == 0) {
      #pragma unroll
      for (int j = 0; j < 4; j++) {
        sr1[wv][j * 16 + lr] = st1[j];
        sr2[wv][j * 16 + lr] = st2[j];
      }
    }
    __syncthreads();
    if (t < 128) {
      int ch = t >> 6, c6 = t & 63;
      float a1 = sr1[ch][c6] + sr1[ch + 2][c6];
      float a2 = sr2[ch][c6] + sr2[ch + 2][c6];
      float2 o = { a1, a2 };
      *(float2*)(partOut + ((size_t)mb * CC + n0 + t) * 2) = o;
    }
  }
}

// conv wrapper with grouped block swizzle (SWZ_G m-tiles x 8 n-tiles per group)
#define SWZ_G 64

template<bool STATS>
__global__ __launch_bounds__(256, 2)
void k_mg(const u32* __restrict__ A, const u32* __restrict__ Bp,
          const float* __restrict__ bias, float* __restrict__ Cmat,
          int mtiles, float* __restrict__ partOut)
{
  int id = blockIdx.y * gridDim.x + blockIdx.x;
  int g = id / (SWZ_G * 8);
  int rem = id - g * (SWZ_G * 8);
  int gsz = mtiles - g * SWZ_G; if (gsz > SWZ_G) gsz = SWZ_G;
  int mt = g * SWZ_G + rem % gsz;
  int nt = rem / gsz;
  mg_body<1, STATS>(A, Bp, bias, Cmat, mt * 128, nt * 128, partOut, mt);
}

__global__ __launch_bounds__(256, 2)
void k_heads(const u32* __restrict__ ctxp, const u32* __restrict__ wplh,
             const float* __restrict__ lb, float* __restrict__ out)
{
  int p, w;
  head_entry(blockIdx.y, &p, &w);
  mg_body<2, false>(ctxp + (size_t)p * BB * 1024,
                    wplh + (size_t)w * 1048576,
                    lb + (size_t)w * CC,
                    out + (size_t)blockIdx.y * BB * CC,
                    (blockIdx.x >> 3) * 128, (blockIdx.x & 7) * 128,
                    nullptr, 0);
}

// ---------------------------------------------------------------- launch

extern "C" void kernel_launch(void* const* d_in, const int* in_sizes, int n_in,
                              void* d_out, int out_size, void* d_ws, size_t ws_size,
                              hipStream_t stream)
{
  const float* x   = (const float*)d_in[0];
  const float* bng = (const float*)d_in[1];
  const float* bnb = (const float*)d_in[2];
  const float* cw  = (const float*)d_in[3];
  const float* cb  = (const float*)d_in[4];
  const float* lw  = (const float*)d_in[5];
  const float* lb  = (const float*)d_in[6];
  float* out = (float*)d_out;
  float* ws  = (float*)d_ws;

  const size_t W = ws_size / 4;           // 4-byte words
  const size_t SZ_WHI  = 3ull * 524288;   // conv weights, RNE hi-only
  const size_t SZ_WPL  = 12ull * 1048576; // head weights, trunc hi+lo
  const size_t SZ_XT   = 256ull * 49 * 1024;
  const size_t SZ_PS   = 6400ull * 512;   // pooled RNE hi-only (u32)
  const size_t SZ_CTX  = 6400ull * 1024;
  const size_t SZ_CTXP = 6400ull * 1024;
  const size_t SZ_XS   = 50176;
  const size_t SZ_SS   = 25ull * 1024;

  auto need = [&](int pc, bool xt) -> size_t {
    return SZ_WHI + SZ_WPL + (xt ? SZ_XT : 0)
         + (size_t)pc * 2304 * 1024          // bufF (fp32)
         + (size_t)pc * 2304 * 512           // bufS (RNE hi-only)
         + SZ_PS + SZ_CTX + SZ_CTXP + 2 * SZ_XS + 2 * SZ_SS
         + (size_t)pc * 18 * 1024 * 2;
  };
  int PC; bool useXT;
  if      (W >= need(25, true))  { PC = 25; useXT = true;  }
  else if (W >= need(5, true))   { PC = 5;  useXT = true;  }
  else if (W >= need(1, true))   { PC = 1;  useXT = true;  }
  else                           { PC = 1;  useXT = false; }

  u32*   whi    = (u32*)ws;
  u32*   wpl    = whi + SZ_WHI;
  float* xtg    = (float*)(wpl + SZ_WPL);
  float* bufF   = xtg + (useXT ? SZ_XT : 0);
  u32*   bufS   = (u32*)(bufF + (size_t)PC * 2304 * 1024);
  u32*   pooledS= bufS + (size_t)PC * 2304 * 512;
  float* ctx    = (float*)(pooledS + SZ_PS);
  u32*   ctxp   = (u32*)(ctx + SZ_CTX);
  float* xs1    = (float*)(ctxp + SZ_CTXP);
  float* xs2    = xs1 + SZ_XS;
  float* ssc    = xs2 + SZ_XS;
  float* ssh    = ssc + SZ_SS;
  float* part   = ssh + SZ_SS;

  // weight pre-split: conv (RNE hi-only) + heads (trunc hi+lo)
  k_wsplit_rn<<<(int)(SZ_WHI / 256), 256, 0, stream>>>(cw, whi, (int)SZ_WHI);
  k_wsplit<<<(12 * 1048576) / 256, 256, 0, stream>>>(lw, wpl, 12 * 1048576);
  if (useXT) k_transpose<<<dim3(256, 8), 256, 0, stream>>>(x, xtg);
  k_xsums<<<196, 256, 0, stream>>>(x, xs1, xs2);
  k_stats1<<<dim3(25, 4), 256, 0, stream>>>(xs1, xs2, bng, bnb, ssc, ssh);

  for (int pbase = 0; pbase < NP; pbase += PC) {
    const int rows = PC * 2304;
    const int mtiles = PC * 18;
    const dim3 gconv(mtiles, 8);
    // A1: BN1+relu+RNE from xt (or x fallback) -> bufS
    if (useXT)
      k_absplit<1><<<rows / 8, 256, 0, stream>>>(xtg, ssc, ssh, bufS, pbase);
    else
      k_absplit<2><<<rows / 8, 256, 0, stream>>>(x, ssc, ssh, bufS, pbase);
    // conv1: bufS -> bufF, col stats -> part
    k_mg<true><<<gconv, 256, 0, stream>>>(bufS, whi, cb, bufF, mtiles, part);
    k_statsfin<<<dim3(PC, 4), 256, 0, stream>>>(part, bng + CC, bnb + CC, ssc, ssh, pbase);
    // A2: BN2+relu+RNE from bufF -> bufS
    k_absplit<0><<<rows / 8, 256, 0, stream>>>(bufF, ssc, ssh, bufS, pbase);
    // conv2: bufS -> bufF, stats -> part
    k_mg<true><<<gconv, 256, 0, stream>>>(bufS, whi + 524288, cb + CC,
                                          bufF, mtiles, part);
    k_statsfin<<<dim3(PC, 4), 256, 0, stream>>>(part, bng + 2 * CC, bnb + 2 * CC, ssc, ssh, pbase);
    // BN3+relu+pool, RNE output -> pooledS slice
    k_pool<<<PC * 256, 256, 0, stream>>>(bufF, ssc, ssh, pooledS, pbase);
  }

  // conv3 over all pooled rows -> ctx
  k_mg<false><<<dim3(50, 8), 256, 0, stream>>>(pooledS, whi + 2 * 524288,
                                               cb + 2 * CC, ctx, 50, nullptr);
  // ctx -> split (trunc hi+lo), then heads (3-product path)
  k_wsplit<<<(6400 * 1024) / 256, 256, 0, stream>>>(ctx, ctxp, 6400 * 1024);
  k_heads<<<dim3(16, 120), 256, 0, stream>>>(ctxp, wpl, lb, out);
}

// Round 15
// 739.187 us; speedup vs baseline: 1.6415x; 1.2622x over previous
//
#include <hip/hip_runtime.h>
#include <hip/hip_bf16.h>
#include <stdint.h>

#define BB 256
#define CC 1024
#define NP 25
#define EPS 1e-5f

typedef __attribute__((ext_vector_type(8))) short bf16x8;
typedef __attribute__((ext_vector_type(4))) float f32x4;
typedef unsigned int u32;

#define MFMA16(A, B, C) __builtin_amdgcn_mfma_f32_16x16x32_bf16(A, B, C, 0, 0, 0)

// async global->LDS, 16B per lane; LDS dest = wave-uniform base + lane*16
__device__ __forceinline__ void gload16(const u32* g, u32* l)
{
  __builtin_amdgcn_global_load_lds(
      (const __attribute__((address_space(1))) u32*)g,
      (__attribute__((address_space(3))) u32*)l, 16, 0, 0);
}

// ---------------------------------------------------------------- utils

__device__ __forceinline__ void head_entry(int j, int* pp, int* ww)
{
  int cnt = 0;
  for (int y1 = 0; y1 < 5; y1++)
    for (int x1 = 0; x1 < 5; x1++) {
      int p = y1 * 5 + x1;
      int y2 = y1 + 2, x2 = x1 + 2;
      if (y2 == 2 || y2 == 3)
        for (int s = 0; s < 3; s++) { if (y2 + s + 1 > 6) break; if (cnt == j) { *pp = p; *ww = 0 + s; return; } cnt++; }
      if (y1 == 3 || y1 == 4)
        for (int s = 0; s < 3; s++) { if (y1 - (s + 1) < 0) break; if (cnt == j) { *pp = p; *ww = 3 + s; return; } cnt++; }
      if (x2 == 2 || x2 == 3)
        for (int s = 0; s < 3; s++) { if (x2 + s + 1 > 6) break; if (cnt == j) { *pp = p; *ww = 6 + s; return; } cnt++; }
      if (x1 == 3 || x1 == 4)
        for (int s = 0; s < 3; s++) { if (x1 - (s + 1) < 0) break; if (cnt == j) { *pp = p; *ww = 9 + s; return; } cnt++; }
    }
}

// round-to-nearest-even bf16 (keep high 16 bits)
__device__ __forceinline__ u32 rne_hi(u32 x)
{
  return (x + 0x7FFFu + ((x >> 16) & 1u)) & 0xFFFF0000u;
}

// pack two floats as RNE bf16 pair into one u32 (a -> low, b -> high)
__device__ __forceinline__ u32 rne_pack(float a, float b)
{
  return (rne_hi(__float_as_uint(a)) >> 16) | rne_hi(__float_as_uint(b));
}

__device__ __forceinline__ float bflo(u32 u) { return __uint_as_float(u << 16); }
__device__ __forceinline__ float bfhi(u32 u) { return __uint_as_float(u & 0xFFFF0000u); }

// ------------------------------------------------- layer-1 stats from x

__global__ void k_xsums(const float* __restrict__ x, float* __restrict__ xs1,
                        float* __restrict__ xs2)
{
  int pos = blockIdx.x * 256 + threadIdx.x;   // < 50176
  float s1 = 0.f, s2 = 0.f;
  for (int b = 0; b < BB; b++) {
    float v = x[(size_t)b * 50176 + pos];
    s1 += v; s2 = fmaf(v, v, s2);
  }
  xs1[pos] = s1; xs2[pos] = s2;
}

__global__ void k_stats1(const float* __restrict__ xs1, const float* __restrict__ xs2,
                         const float* __restrict__ gam, const float* __restrict__ bet,
                         float* __restrict__ ssc, float* __restrict__ ssh)
{
  int p = blockIdx.x;
  int c = blockIdx.y * 256 + threadIdx.x;
  int y1 = p / 5, x1 = p % 5;
  float s1 = 0.f, s2 = 0.f;
  for (int dy = 0; dy < 3; dy++)
    for (int dx = 0; dx < 3; dx++) {
      int pos = c * 49 + (y1 + dy) * 7 + (x1 + dx);
      s1 += xs1[pos]; s2 += xs2[pos];
    }
  const float inv = 1.0f / 2304.0f;
  float mean = s1 * inv;
  float var  = s2 * inv - mean * mean;
  float rs   = rsqrtf(var + EPS);
  float sc   = rs * gam[c];
  ssc[(size_t)p * CC + c] = sc;
  ssh[(size_t)p * CC + c] = bet[c] - mean * sc;
}

// ------------------------- one-time x transpose: x[b][c][yx] -> xt[b][yx][c]

__global__ void k_transpose(const float* __restrict__ x, float* __restrict__ xt)
{
  __shared__ float tile[128][51];
  int b = blockIdx.x, cg = blockIdx.y;
  const float* src = x + (size_t)b * 50176 + (size_t)cg * 128 * 49;
  for (int idx = threadIdx.x; idx < 6272; idx += 256)
    tile[idx / 49][idx % 49] = src[idx];
  __syncthreads();
  float* dst = xt + (size_t)b * 49 * 1024 + cg * 128;
  for (int pp = 0; pp < 50; pp += 2) {
    int p = pp + (threadIdx.x >> 7);
    int i = threadIdx.x & 127;
    if (p < 49) dst[(size_t)p * 1024 + i] = tile[i][p];
  }
}

// ---------- weights: RNE hi-only layout (512-u32 rows, slab = 16 u32)

__global__ void k_wsplit_rn(const float* __restrict__ w, u32* __restrict__ dst, int total)
{
  int g = blockIdx.x * 256 + threadIdx.x;
  if (g >= total) return;
  int row = g >> 9;
  int idx = g & 511;
  const float* src = w + ((size_t)row << 10) + 2 * idx;
  dst[g] = rne_pack(src[0], src[1]);
}

// ------------- A-operand affine+relu+RNE into hi-only gload layout (512-u32 rows)
// MODE 0: src = bf16-pair linear rows (u32, 512/row) from conv output;
// MODE 1: src = xt (fp32), patch row-map (conv1 A);
// MODE 2: src = x (fp32), strided reads (no-xt fallback).

template<int MODE>
__global__ void k_absplit(const void* __restrict__ srcv,
                          const float* __restrict__ ssc, const float* __restrict__ ssh,
                          u32* __restrict__ dst, int pbase)
{
  int r = blockIdx.x * 8 + (threadIdx.x >> 5);   // local row
  int slab = threadIdx.x & 31;
  int pg;
  const float* sp = nullptr;
  const float* xb = nullptr;
  const u32*   su = nullptr;
  if (MODE == 0) {
    pg = pbase + r / 2304;
    su = (const u32*)srcv + (size_t)r * 512 + slab * 16;
  } else {
    int pl = r / 2304, q = r - pl * 2304;
    pg = pbase + pl;
    int b = q / 9, yx = q - b * 9;
    int pos = (pg / 5 + yx / 3) * 7 + (pg % 5) + (yx % 3);
    if (MODE == 1) sp = (const float*)srcv + ((size_t)b * 49 + pos) * 1024 + slab * 32;
    else           xb = (const float*)srcv + (size_t)b * 50176 + (size_t)slab * 32 * 49 + pos;
  }
  const float* scp = ssc + (size_t)pg * CC + slab * 32;
  const float* shp = ssh + (size_t)pg * CC + slab * 32;
  u32 hi[16];
  #pragma unroll
  for (int j = 0; j < 8; j++) {
    float4 f;
    if (MODE == 0) {
      u32 p0 = su[2 * j], p1 = su[2 * j + 1];
      f.x = bflo(p0); f.y = bfhi(p0); f.z = bflo(p1); f.w = bfhi(p1);
    } else if (MODE == 2) {
      f.x = xb[(size_t)(4 * j + 0) * 49]; f.y = xb[(size_t)(4 * j + 1) * 49];
      f.z = xb[(size_t)(4 * j + 2) * 49]; f.w = xb[(size_t)(4 * j + 3) * 49];
    } else {
      f = *(const float4*)(sp + 4 * j);
    }
    float4 s = *(const float4*)(scp + 4 * j);
    float4 h = *(const float4*)(shp + 4 * j);
    f.x = fmaxf(fmaf(f.x, s.x, h.x), 0.f);
    f.y = fmaxf(fmaf(f.y, s.y, h.y), 0.f);
    f.z = fmaxf(fmaf(f.z, s.z, h.z), 0.f);
    f.w = fmaxf(fmaf(f.w, s.w, h.w), 0.f);
    hi[2 * j]     = rne_pack(f.x, f.y);
    hi[2 * j + 1] = rne_pack(f.z, f.w);
  }
  u32* op = dst + (size_t)r * 512 + slab * 16;
  *(uint4*)(op + 0)  = make_uint4(hi[0], hi[1], hi[2], hi[3]);
  *(uint4*)(op + 4)  = make_uint4(hi[4], hi[5], hi[6], hi[7]);
  *(uint4*)(op + 8)  = make_uint4(hi[8], hi[9], hi[10], hi[11]);
  *(uint4*)(op + 12) = make_uint4(hi[12], hi[13], hi[14], hi[15]);
}

// ------------------- finalize BN stats from per-mblock partials (18/patch)

__global__ void k_statsfin(const float* __restrict__ part, const float* __restrict__ gam,
                           const float* __restrict__ bet, float* __restrict__ ssc,
                           float* __restrict__ ssh, int pbase)
{
  int pl = blockIdx.x;
  int c  = blockIdx.y * 256 + threadIdx.x;
  float s1 = 0.f, s2 = 0.f;
  for (int mb = 0; mb < 18; mb++) {
    const float* pp = part + ((size_t)(pl * 18 + mb) * CC + c) * 2;
    s1 += pp[0]; s2 += pp[1];
  }
  const float inv = 1.0f / 2304.0f;
  float mean = s1 * inv;
  float var  = s2 * inv - mean * mean;
  float rs   = rsqrtf(var + EPS);
  float sc   = rs * gam[c];
  int pg = pbase + pl;
  ssc[(size_t)pg * CC + c] = sc;
  ssh[(size_t)pg * CC + c] = bet[c] - mean * sc;
}

// ---- BN3 affine+relu + 3x3 mean pooling; input bf16-pairs, output RNE hi-only

__global__ void k_pool(const u32* __restrict__ h, const float* __restrict__ ssc,
                       const float* __restrict__ ssh, u32* __restrict__ apool, int pbase)
{
  int row = blockIdx.x;                 // local: pl*256 + b
  int pl = row >> 8;
  int pg = pbase + pl;
  int c = threadIdx.x * 4;
  float4 sc = *(const float4*)(ssc + (size_t)pg * CC + c);
  float4 sh = *(const float4*)(ssh + (size_t)pg * CC + c);
  const u32* hp = h + (size_t)row * 9 * 512 + (c >> 1);
  float4 s = {0.f, 0.f, 0.f, 0.f};
  #pragma unroll
  for (int yx = 0; yx < 9; yx++) {
    uint2 pp = *(const uint2*)(hp + (size_t)yx * 512);
    float4 v = { bflo(pp.x), bfhi(pp.x), bflo(pp.y), bfhi(pp.y) };
    s.x += fmaxf(fmaf(v.x, sc.x, sh.x), 0.f);
    s.y += fmaxf(fmaf(v.y, sc.y, sh.y), 0.f);
    s.z += fmaxf(fmaf(v.z, sc.z, sh.z), 0.f);
    s.w += fmaxf(fmaf(v.w, sc.w, sh.w), 0.f);
  }
  const float inv9 = 1.0f / 9.0f;
  uint2 o = { rne_pack(s.x * inv9, s.y * inv9), rne_pack(s.z * inv9, s.w * inv9) };
  u32* op = apool + ((size_t)(pbase * 256) + row) * 512 + (c >> 1);
  *(uint2*)op = o;
}

// ------------------------------------------------------------ MFMA GEMM core
// C[m][n] = sum_k A[m][k] * B[n][k] + bias[n]; staged via global_load_lds.
// B is ALWAYS RNE hi-only (512-u32 rows, granule g^((row>>1)&3), 2-way max).
// CFG=1 (convs): A RNE hi-only (as B), 1 product.
// CFG=2 (heads): A trunc hi/lo (1024-u32 rows, granule g^(row&7)), 2 products
//                (ah*bh + al*bh -> a exact to 2^-16, b RNE).
// OUT=0: fp32 rows (float*, stride CC)
// OUT=1: RNE bf16-pair rows (u32*, stride 512) via lane-pair shfl pack
// OUT=2: trunc hi/lo gload rows (u32*, stride 1024, [slab|16hi|16lo])
// STATS: per-block column sum/sumsq -> partOut[mb][col][2].

template<int CFG, int OUT, bool STATS>
__device__ __forceinline__ void mg_body(
    const u32* __restrict__ Agl, const u32* __restrict__ Bp,
    const float* __restrict__ bias, void* __restrict__ Cptr,
    int m0, int n0, float* __restrict__ partOut, int mb)
{
  constexpr int ARS   = (CFG == 1) ? 512 : 1024;  // A global row stride (u32)
  constexpr int ALROW = (CFG == 1) ? 16 : 32;     // A LDS row (u32)
  __shared__ u32 sA[2][128 * ALROW];
  __shared__ u32 sB[2][128 * 16];
  __shared__ float sr1[4][64];
  __shared__ float sr2[4][64];

  const int t = threadIdx.x;
  const int l = t & 63, wv = t >> 6;
  const int lr = l & 15, lk = l >> 4;
  const int wm = (wv >> 1) * 64, wn = (wv & 1) * 64;

  // fragment read offsets (u32) with granule XOR swizzle
  int fAh[4], fAl[4], fBh[4];
  #pragma unroll
  for (int i = 0; i < 4; i++) {
    int Ra = wm + i * 16 + lr;
    int Rb = wn + i * 16 + lr;
    if (CFG == 1) {
      fAh[i] = Ra * 16 + ((lk ^ ((Ra >> 1) & 3)) << 2);
      fAl[i] = 0;
    } else {
      fAh[i] = Ra * 32 + ((lk ^ (Ra & 7)) << 2);
      fAl[i] = Ra * 32 + (((4 + lk) ^ (Ra & 7)) << 2);
    }
    fBh[i] = Rb * 16 + ((lk ^ ((Rb >> 1) & 3)) << 2);
  }

  // A gload: CFG1 -> 2 chunks of 16 rows; CFG2 -> 4 chunks of 8 rows
  constexpr int ANQ = (CFG == 1) ? 2 : 4;
  int arow_[ANQ], ag[ANQ], adst[ANQ];
  #pragma unroll
  for (int q = 0; q < ANQ; q++) {
    if (CFG == 1) {
      int rr = wv * 32 + q * 16 + (l >> 2);
      arow_[q] = rr;
      ag[q] = (((l & 3) ^ ((rr >> 1) & 3)) << 2);
      adst[q] = (wv * 32 + q * 16) * 16;
    } else {
      int rr = wv * 32 + q * 8 + (l >> 3);
      arow_[q] = rr;
      ag[q] = (((l & 7) ^ (rr & 7)) << 2);
      adst[q] = (wv * 32 + q * 8) * 32;
    }
  }
  // B gload: always 2 chunks of 16 rows (16-u32 rows)
  int brow[2], bg[2], bdst[2];
  #pragma unroll
  for (int q = 0; q < 2; q++) {
    int rr = wv * 32 + q * 16 + (l >> 2);
    brow[q] = rr;
    bg[q] = (((l & 3) ^ ((rr >> 1) & 3)) << 2);
    bdst[q] = (wv * 32 + q * 16) * 16;
  }
  const u32* Brow = Bp + (size_t)n0 * 512;
  const u32* Agr  = Agl + (size_t)m0 * ARS;

  f32x4 acc[4][4];
  #pragma unroll
  for (int i = 0; i < 4; i++)
    #pragma unroll
    for (int j = 0; j < 4; j++) { f32x4 z = {0.f, 0.f, 0.f, 0.f}; acc[i][j] = z; }

  // prologue: stage slab 0
  #pragma unroll
  for (int q = 0; q < 2; q++)
    gload16(Brow + (size_t)brow[q] * 512 + bg[q], &sB[0][bdst[q]]);
  #pragma unroll
  for (int q = 0; q < ANQ; q++)
    gload16(Agr + (size_t)arow_[q] * ARS + ag[q], &sA[0][adst[q]]);
  __syncthreads();

  #pragma unroll 1
  for (int it = 0; it < 32; ++it) {
    const int cur = it & 1, nxt = cur ^ 1;
    const bool pf = (it < 31);
    if (pf) {
      const int soA = (CFG == 1) ? ((it + 1) << 4) : ((it + 1) << 5);
      const int soB = (it + 1) << 4;
      #pragma unroll
      for (int q = 0; q < 2; q++)
        gload16(Brow + (size_t)brow[q] * 512 + soB + bg[q], &sB[nxt][bdst[q]]);
      #pragma unroll
      for (int q = 0; q < ANQ; q++)
        gload16(Agr + (size_t)arow_[q] * ARS + soA + ag[q], &sA[nxt][adst[q]]);
    }
    bf16x8 Ah[4], Al_[4], Bh[4];
    #pragma unroll
    for (int i = 0; i < 4; i++) {
      Ah[i] = *(const bf16x8*)&sA[cur][fAh[i]];
      Bh[i] = *(const bf16x8*)&sB[cur][fBh[i]];
      if (CFG == 2) Al_[i] = *(const bf16x8*)&sA[cur][fAl[i]];
    }
    #pragma unroll
    for (int i = 0; i < 4; i++)
      #pragma unroll
      for (int j = 0; j < 4; j++) {
        acc[i][j] = MFMA16(Ah[i], Bh[j], acc[i][j]);
        if (CFG == 2) acc[i][j] = MFMA16(Al_[i], Bh[j], acc[i][j]);
      }
    __syncthreads();
  }

  // epilogue: D row = lk*4 + reg, col = lr [m89 layout]; optional col stats
  float* Cf = (float*)Cptr;
  u32*   Cu = (u32*)Cptr;
  float st1[4], st2[4];
  #pragma unroll
  for (int j = 0; j < 4; j++) { st1[j] = 0.f; st2[j] = 0.f; }
  #pragma unroll
  for (int j = 0; j < 4; j++) {
    int ocol = n0 + wn + j * 16 + lr;
    float bj = bias[ocol];
    #pragma unroll
    for (int i = 0; i < 4; i++) {
      int orow = m0 + wm + i * 16 + lk * 4;
      #pragma unroll
      for (int reg = 0; reg < 4; reg++) {
        float v = acc[i][j][reg] + bj;
        if (STATS) { st1[j] += v; st2[j] = fmaf(v, v, st2[j]); }
        int row = orow + reg;
        if (OUT == 0) {
          Cf[(size_t)row * CC + ocol] = v;
        } else {
          float pv = __shfl_xor(v, 1);
          if (!(lr & 1)) {
            if (OUT == 1) {
              Cu[(size_t)row * 512 + (ocol >> 1)] = rne_pack(v, pv);
            } else {
              int slab = ocol >> 5, jj = (ocol & 31) >> 1;
              u32 ua = __float_as_uint(v), ub = __float_as_uint(pv);
              u32 hi = (ua >> 16) | (ub & 0xFFFF0000u);
              float la = v  - __uint_as_float(ua & 0xFFFF0000u);
              float lb = pv - __uint_as_float(ub & 0xFFFF0000u);
              u32 lo = (__float_as_uint(la) >> 16) |
                       (__float_as_uint(lb) & 0xFFFF0000u);
              u32* cp = Cu + (size_t)row * 1024 + slab * 32 + jj;
              cp[0]  = hi;
              cp[16] = lo;
            }
          }
        }
      }
    }
  }
  if (STATS) {
    #pragma unroll
    for (int j = 0; j < 4; j++) {
      st1[j] += __shfl_xor(st1[j], 16, 64);
      st1[j] += __shfl_xor(st1[j], 32, 64);
      st2[j] += __shfl_xor(st2[j], 16, 64);
      st2[j] += __shfl_xor(st2[j], 32, 64);
    }
    if (lk == 0) {
      #pragma unroll
      for (int j = 0; j < 4; j++) {
        sr1[wv][j * 16 + lr] = st1[j];
        sr2[wv][j * 16 + lr] = st2[j];
      }
    }
    __syncthreads();
    if (t < 128) {
      int ch = t >> 6, c6 = t & 63;
      float a1 = sr1[ch][c6] + sr1[ch + 2][c6];
      float a2 = sr2[ch][c6] + sr2[ch + 2][c6];
      float2 o = { a1, a2 };
      *(float2*)(partOut + ((size_t)mb * CC + n0 + t) * 2) = o;
    }
  }
}

// conv wrapper with grouped block swizzle (SWZ_G m-tiles x 8 n-tiles per group)
#define SWZ_G 64

template<int OUT, bool STATS>
__global__ __launch_bounds__(256, 2)
void k_mg(const u32* __restrict__ A, const u32* __restrict__ Bp,
          const float* __restrict__ bias, void* __restrict__ Cptr,
          int mtiles, float* __restrict__ partOut)
{
  int id = blockIdx.y * gridDim.x + blockIdx.x;
  int g = id / (SWZ_G * 8);
  int rem = id - g * (SWZ_G * 8);
  int gsz = mtiles - g * SWZ_G; if (gsz > SWZ_G) gsz = SWZ_G;
  int mt = g * SWZ_G + rem % gsz;
  int nt = rem / gsz;
  mg_body<1, OUT, STATS>(A, Bp, bias, Cptr, mt * 128, nt * 128, partOut, mt);
}

__global__ __launch_bounds__(256, 2)
void k_heads(const u32* __restrict__ ctxp, const u32* __restrict__ wplh,
             const float* __restrict__ lb, float* __restrict__ out)
{
  int p, w;
  head_entry(blockIdx.y, &p, &w);
  mg_body<2, 0, false>(ctxp + (size_t)p * BB * 1024,
                       wplh + (size_t)w * 524288,
                       lb + (size_t)w * CC,
                       out + (size_t)blockIdx.y * BB * CC,
                       (blockIdx.x >> 3) * 128, (blockIdx.x & 7) * 128,
                       nullptr, 0);
}

// ---------------------------------------------------------------- launch

extern "C" void kernel_launch(void* const* d_in, const int* in_sizes, int n_in,
                              void* d_out, int out_size, void* d_ws, size_t ws_size,
                              hipStream_t stream)
{
  const float* x   = (const float*)d_in[0];
  const float* bng = (const float*)d_in[1];
  const float* bnb = (const float*)d_in[2];
  const float* cw  = (const float*)d_in[3];
  const float* cb  = (const float*)d_in[4];
  const float* lw  = (const float*)d_in[5];
  const float* lb  = (const float*)d_in[6];
  float* out = (float*)d_out;

  const size_t W = ws_size / 4;           // 4-byte words
  const size_t SZ_WHI  = 3ull * 524288;   // conv weights, RNE hi-only
  const size_t SZ_WPL  = 12ull * 524288;  // head weights, RNE hi-only
  const size_t SZ_XT   = 256ull * 49 * 1024;
  const size_t SZ_PS   = 6400ull * 512;   // pooled RNE hi-only (u32)
  const size_t SZ_CTXP = 6400ull * 1024;  // ctx trunc hi/lo gload (u32)
  const size_t SZ_XS   = 50176;
  const size_t SZ_SS   = 25ull * 1024;

  auto need = [&](int pc, bool xt) -> size_t {
    return SZ_WHI + SZ_WPL + (xt ? SZ_XT : 0)
         + 2ull * pc * 2304 * 512           // bufS + bufO (u32)
         + SZ_PS + SZ_CTXP + 2 * SZ_XS + 2 * SZ_SS
         + (size_t)pc * 18 * 1024 * 2;
  };
  int PC; bool useXT;
  if      (W >= need(25, true))  { PC = 25; useXT = true;  }
  else if (W >= need(5, true))   { PC = 5;  useXT = true;  }
  else if (W >= need(1, true))   { PC = 1;  useXT = true;  }
  else                           { PC = 1;  useXT = false; }

  u32*   whi    = (u32*)d_ws;
  u32*   wpl    = whi + SZ_WHI;
  float* xtg    = (float*)(wpl + SZ_WPL);
  u32*   bufS   = (u32*)(xtg + (useXT ? SZ_XT : 0));
  u32*   bufO   = bufS + (size_t)PC * 2304 * 512;
  u32*   pooledS= bufO + (size_t)PC * 2304 * 512;
  u32*   ctxp   = pooledS + SZ_PS;
  float* xs1    = (float*)(ctxp + SZ_CTXP);
  float* xs2    = xs1 + SZ_XS;
  float* ssc    = xs2 + SZ_XS;
  float* ssh    = ssc + SZ_SS;
  float* part   = ssh + SZ_SS;

  // weight pre-split: conv + heads, both RNE hi-only
  k_wsplit_rn<<<(int)(SZ_WHI / 256), 256, 0, stream>>>(cw, whi, (int)SZ_WHI);
  k_wsplit_rn<<<(int)(SZ_WPL / 256), 256, 0, stream>>>(lw, wpl, (int)SZ_WPL);
  if (useXT) k_transpose<<<dim3(256, 8), 256, 0, stream>>>(x, xtg);
  k_xsums<<<196, 256, 0, stream>>>(x, xs1, xs2);
  k_stats1<<<dim3(25, 4), 256, 0, stream>>>(xs1, xs2, bng, bnb, ssc, ssh);

  for (int pbase = 0; pbase < NP; pbase += PC) {
    const int rows = PC * 2304;
    const int mtiles = PC * 18;
    const dim3 gconv(mtiles, 8);
    // A1: BN1+relu+RNE from xt (or x fallback) -> bufS
    if (useXT)
      k_absplit<1><<<rows / 8, 256, 0, stream>>>(xtg, ssc, ssh, bufS, pbase);
    else
      k_absplit<2><<<rows / 8, 256, 0, stream>>>(x, ssc, ssh, bufS, pbase);
    // conv1: bufS -> bufO (bf16-pairs), col stats -> part
    k_mg<1, true><<<gconv, 256, 0, stream>>>(bufS, whi, cb, bufO, mtiles, part);
    k_statsfin<<<dim3(PC, 4), 256, 0, stream>>>(part, bng + CC, bnb + CC, ssc, ssh, pbase);
    // A2: BN2+relu+RNE from bufO -> bufS
    k_absplit<0><<<rows / 8, 256, 0, stream>>>(bufO, ssc, ssh, bufS, pbase);
    // conv2: bufS -> bufO (bf16-pairs), stats -> part
    k_mg<1, true><<<gconv, 256, 0, stream>>>(bufS, whi + 524288, cb + CC,
                                             bufO, mtiles, part);
    k_statsfin<<<dim3(PC, 4), 256, 0, stream>>>(part, bng + 2 * CC, bnb + 2 * CC, ssc, ssh, pbase);
    // BN3+relu+pool from bufO, RNE output -> pooledS slice
    k_pool<<<PC * 256, 256, 0, stream>>>(bufO, ssc, ssh, pooledS, pbase);
  }

  // conv3 over all pooled rows -> ctxp (trunc hi/lo gload layout, direct)
  k_mg<2, false><<<dim3(50, 8), 256, 0, stream>>>(pooledS, whi + 2 * 524288,
                                                  cb + 2 * CC, ctxp, 50, nullptr);
  // heads: A = ctxp (2-plane), B = head weights (RNE hi-only), 2 products
  k_heads<<<dim3(16, 120), 256, 0, stream>>>(ctxp, wpl, lb, out);
}

// Round 16
// 666.534 us; speedup vs baseline: 1.8204x; 1.1090x over previous
//
#include <hip/hip_runtime.h>
#include <hip/hip_bf16.h>
#include <stdint.h>

#define BB 256
#define CC 1024
#define NP 25
#define EPS 1e-5f

typedef __attribute__((ext_vector_type(8))) short bf16x8;
typedef __attribute__((ext_vector_type(4))) float f32x4;
typedef unsigned int u32;

#define MFMA16(A, B, C) __builtin_amdgcn_mfma_f32_16x16x32_bf16(A, B, C, 0, 0, 0)

// async global->LDS, 16B per lane; LDS dest = wave-uniform base + lane*16
__device__ __forceinline__ void gload16(const u32* g, u32* l)
{
  __builtin_amdgcn_global_load_lds(
      (const __attribute__((address_space(1))) u32*)g,
      (__attribute__((address_space(3))) u32*)l, 16, 0, 0);
}

// ---------------------------------------------------------------- utils

__device__ __forceinline__ void head_entry(int j, int* pp, int* ww)
{
  int cnt = 0;
  for (int y1 = 0; y1 < 5; y1++)
    for (int x1 = 0; x1 < 5; x1++) {
      int p = y1 * 5 + x1;
      int y2 = y1 + 2, x2 = x1 + 2;
      if (y2 == 2 || y2 == 3)
        for (int s = 0; s < 3; s++) { if (y2 + s + 1 > 6) break; if (cnt == j) { *pp = p; *ww = 0 + s; return; } cnt++; }
      if (y1 == 3 || y1 == 4)
        for (int s = 0; s < 3; s++) { if (y1 - (s + 1) < 0) break; if (cnt == j) { *pp = p; *ww = 3 + s; return; } cnt++; }
      if (x2 == 2 || x2 == 3)
        for (int s = 0; s < 3; s++) { if (x2 + s + 1 > 6) break; if (cnt == j) { *pp = p; *ww = 6 + s; return; } cnt++; }
      if (x1 == 3 || x1 == 4)
        for (int s = 0; s < 3; s++) { if (x1 - (s + 1) < 0) break; if (cnt == j) { *pp = p; *ww = 9 + s; return; } cnt++; }
    }
}

// round-to-nearest-even bf16 (keep high 16 bits)
__device__ __forceinline__ u32 rne_hi(u32 x)
{
  return (x + 0x7FFFu + ((x >> 16) & 1u)) & 0xFFFF0000u;
}

// pack two floats as RNE bf16 pair into one u32 (a -> low, b -> high)
__device__ __forceinline__ u32 rne_pack(float a, float b)
{
  return (rne_hi(__float_as_uint(a)) >> 16) | rne_hi(__float_as_uint(b));
}

__device__ __forceinline__ float bflo(u32 u) { return __uint_as_float(u << 16); }
__device__ __forceinline__ float bfhi(u32 u) { return __uint_as_float(u & 0xFFFF0000u); }

// ------------------------------------------------- layer-1 stats from x

__global__ void k_xsums(const float* __restrict__ x, float* __restrict__ xs1,
                        float* __restrict__ xs2)
{
  int pos = blockIdx.x * 256 + threadIdx.x;   // < 50176
  float s1 = 0.f, s2 = 0.f;
  for (int b = 0; b < BB; b++) {
    float v = x[(size_t)b * 50176 + pos];
    s1 += v; s2 = fmaf(v, v, s2);
  }
  xs1[pos] = s1; xs2[pos] = s2;
}

__global__ void k_stats1(const float* __restrict__ xs1, const float* __restrict__ xs2,
                         const float* __restrict__ gam, const float* __restrict__ bet,
                         float* __restrict__ ssc, float* __restrict__ ssh)
{
  int p = blockIdx.x;
  int c = blockIdx.y * 256 + threadIdx.x;
  int y1 = p / 5, x1 = p % 5;
  float s1 = 0.f, s2 = 0.f;
  for (int dy = 0; dy < 3; dy++)
    for (int dx = 0; dx < 3; dx++) {
      int pos = c * 49 + (y1 + dy) * 7 + (x1 + dx);
      s1 += xs1[pos]; s2 += xs2[pos];
    }
  const float inv = 1.0f / 2304.0f;
  float mean = s1 * inv;
  float var  = s2 * inv - mean * mean;
  float rs   = rsqrtf(var + EPS);
  float sc   = rs * gam[c];
  ssc[(size_t)p * CC + c] = sc;
  ssh[(size_t)p * CC + c] = bet[c] - mean * sc;
}

// ---- fused transpose + BN1 affine + relu + RNE -> bufS (512-u32 rows)
// block (b, cg): stage x[b, cg*128..+127, 0..48] in LDS, then emit all
// (patch, yx) row-segments for this channel group. One wave per segment.

__global__ void k_tsplit(const float* __restrict__ x,
                         const float* __restrict__ ssc, const float* __restrict__ ssh,
                         u32* __restrict__ bufS, int pbase, int pcount)
{
  __shared__ float tile[128][51];
  int b = blockIdx.x, cg = blockIdx.y;
  const float* src = x + (size_t)b * 50176 + (size_t)cg * 128 * 49;
  for (int idx = threadIdx.x; idx < 6272; idx += 256)
    tile[idx / 49][idx % 49] = src[idx];
  __syncthreads();
  const int t = threadIdx.x;
  const int u = t & 63;
  const int segs = pcount * 9;
  for (int sg = t >> 6; sg < segs; sg += 4) {
    int pl = sg / 9, yx = sg - pl * 9;
    int p = pbase + pl;
    int pos = (p / 5 + yx / 3) * 7 + (p % 5) + (yx % 3);
    int c0 = cg * 128 + u * 2;
    float2 sc = *(const float2*)(ssc + (size_t)p * CC + c0);
    float2 sh = *(const float2*)(ssh + (size_t)p * CC + c0);
    float v0 = fmaxf(fmaf(tile[u * 2][pos],     sc.x, sh.x), 0.f);
    float v1 = fmaxf(fmaf(tile[u * 2 + 1][pos], sc.y, sh.y), 0.f);
    bufS[((size_t)pl * 2304 + b * 9 + yx) * 512 + cg * 64 + u] = rne_pack(v0, v1);
  }
}

// ---------- weights: RNE hi-only layout (512-u32 rows, slab = 16 u32)

__global__ void k_wsplit_rn(const float* __restrict__ w, u32* __restrict__ dst, int total)
{
  int g = blockIdx.x * 256 + threadIdx.x;
  if (g >= total) return;
  int row = g >> 9;
  int idx = g & 511;
  const float* src = w + ((size_t)row << 10) + 2 * idx;
  dst[g] = rne_pack(src[0], src[1]);
}

// ------------- conv2-A: BN2 affine + relu + RNE (bf16-pair src -> bufS)

__global__ void k_absplit(const u32* __restrict__ src,
                          const float* __restrict__ ssc, const float* __restrict__ ssh,
                          u32* __restrict__ dst, int pbase)
{
  int r = blockIdx.x * 8 + (threadIdx.x >> 5);   // local row
  int slab = threadIdx.x & 31;
  int pg = pbase + r / 2304;
  const u32* su = src + (size_t)r * 512 + slab * 16;
  const float* scp = ssc + (size_t)pg * CC + slab * 32;
  const float* shp = ssh + (size_t)pg * CC + slab * 32;
  u32 hi[16];
  #pragma unroll
  for (int j = 0; j < 8; j++) {
    u32 p0 = su[2 * j], p1 = su[2 * j + 1];
    float4 f = { bflo(p0), bfhi(p0), bflo(p1), bfhi(p1) };
    float4 s = *(const float4*)(scp + 4 * j);
    float4 h = *(const float4*)(shp + 4 * j);
    f.x = fmaxf(fmaf(f.x, s.x, h.x), 0.f);
    f.y = fmaxf(fmaf(f.y, s.y, h.y), 0.f);
    f.z = fmaxf(fmaf(f.z, s.z, h.z), 0.f);
    f.w = fmaxf(fmaf(f.w, s.w, h.w), 0.f);
    hi[2 * j]     = rne_pack(f.x, f.y);
    hi[2 * j + 1] = rne_pack(f.z, f.w);
  }
  u32* op = dst + (size_t)r * 512 + slab * 16;
  *(uint4*)(op + 0)  = make_uint4(hi[0], hi[1], hi[2], hi[3]);
  *(uint4*)(op + 4)  = make_uint4(hi[4], hi[5], hi[6], hi[7]);
  *(uint4*)(op + 8)  = make_uint4(hi[8], hi[9], hi[10], hi[11]);
  *(uint4*)(op + 12) = make_uint4(hi[12], hi[13], hi[14], hi[15]);
}

// ------------------- finalize BN stats from per-mblock partials (18/patch)

__global__ void k_statsfin(const float* __restrict__ part, const float* __restrict__ gam,
                           const float* __restrict__ bet, float* __restrict__ ssc,
                           float* __restrict__ ssh, int pbase)
{
  int pl = blockIdx.x;
  int c  = blockIdx.y * 256 + threadIdx.x;
  float s1 = 0.f, s2 = 0.f;
  for (int mb = 0; mb < 18; mb++) {
    const float* pp = part + ((size_t)(pl * 18 + mb) * CC + c) * 2;
    s1 += pp[0]; s2 += pp[1];
  }
  const float inv = 1.0f / 2304.0f;
  float mean = s1 * inv;
  float var  = s2 * inv - mean * mean;
  float rs   = rsqrtf(var + EPS);
  float sc   = rs * gam[c];
  int pg = pbase + pl;
  ssc[(size_t)pg * CC + c] = sc;
  ssh[(size_t)pg * CC + c] = bet[c] - mean * sc;
}

// ---- BN3 affine+relu + 3x3 mean pooling; input bf16-pairs, output RNE hi-only

__global__ void k_pool(const u32* __restrict__ h, const float* __restrict__ ssc,
                       const float* __restrict__ ssh, u32* __restrict__ apool, int pbase)
{
  int row = blockIdx.x;                 // local: pl*256 + b
  int pl = row >> 8;
  int pg = pbase + pl;
  int c = threadIdx.x * 4;
  float4 sc = *(const float4*)(ssc + (size_t)pg * CC + c);
  float4 sh = *(const float4*)(ssh + (size_t)pg * CC + c);
  const u32* hp = h + (size_t)row * 9 * 512 + (c >> 1);
  float4 s = {0.f, 0.f, 0.f, 0.f};
  #pragma unroll
  for (int yx = 0; yx < 9; yx++) {
    uint2 pp = *(const uint2*)(hp + (size_t)yx * 512);
    float4 v = { bflo(pp.x), bfhi(pp.x), bflo(pp.y), bfhi(pp.y) };
    s.x += fmaxf(fmaf(v.x, sc.x, sh.x), 0.f);
    s.y += fmaxf(fmaf(v.y, sc.y, sh.y), 0.f);
    s.z += fmaxf(fmaf(v.z, sc.z, sh.z), 0.f);
    s.w += fmaxf(fmaf(v.w, sc.w, sh.w), 0.f);
  }
  const float inv9 = 1.0f / 9.0f;
  uint2 o = { rne_pack(s.x * inv9, s.y * inv9), rne_pack(s.z * inv9, s.w * inv9) };
  u32* op = apool + ((size_t)(pbase * 256) + row) * 512 + (c >> 1);
  *(uint2*)op = o;
}

// ------------------------------------------------------------ MFMA GEMM core
// C[m][n] = sum_k A[m][k] * B[n][k] + bias[n]; staged via global_load_lds.
// B is ALWAYS RNE hi-only (512-u32 rows, granule g^((row>>1)&3), 2-way max).
// CFG=1 (convs): A RNE hi-only (as B), 1 product.
// CFG=2 (heads): A trunc hi/lo (1024-u32 rows, granule g^(row&7)), 2 products.
// OUT=0 fp32 rows; OUT=1 RNE bf16-pair rows (512-u32); OUT=2 trunc hi/lo rows.
// STATS: per-block column sum/sumsq -> partOut[mb][col][2].
// Stats scratch aliases sA (dead after the K-loop) -> conv LDS = 32 KB.

template<int CFG, int OUT, bool STATS>
__device__ __forceinline__ void mg_body(
    const u32* __restrict__ Agl, const u32* __restrict__ Bp,
    const float* __restrict__ bias, void* __restrict__ Cptr,
    int m0, int n0, float* __restrict__ partOut, int mb)
{
  constexpr int ARS   = (CFG == 1) ? 512 : 1024;  // A global row stride (u32)
  constexpr int ALROW = (CFG == 1) ? 16 : 32;     // A LDS row (u32)
  __shared__ u32 sA[2][128 * ALROW];
  __shared__ u32 sB[2][128 * 16];

  const int t = threadIdx.x;
  const int l = t & 63, wv = t >> 6;
  const int lr = l & 15, lk = l >> 4;
  const int wm = (wv >> 1) * 64, wn = (wv & 1) * 64;

  // fragment read offsets (u32) with granule XOR swizzle
  int fAh[4], fAl[4], fBh[4];
  #pragma unroll
  for (int i = 0; i < 4; i++) {
    int Ra = wm + i * 16 + lr;
    int Rb = wn + i * 16 + lr;
    if (CFG == 1) {
      fAh[i] = Ra * 16 + ((lk ^ ((Ra >> 1) & 3)) << 2);
      fAl[i] = 0;
    } else {
      fAh[i] = Ra * 32 + ((lk ^ (Ra & 7)) << 2);
      fAl[i] = Ra * 32 + (((4 + lk) ^ (Ra & 7)) << 2);
    }
    fBh[i] = Rb * 16 + ((lk ^ ((Rb >> 1) & 3)) << 2);
  }

  // A gload: CFG1 -> 2 chunks of 16 rows; CFG2 -> 4 chunks of 8 rows
  constexpr int ANQ = (CFG == 1) ? 2 : 4;
  int arow_[ANQ], ag[ANQ], adst[ANQ];
  #pragma unroll
  for (int q = 0; q < ANQ; q++) {
    if (CFG == 1) {
      int rr = wv * 32 + q * 16 + (l >> 2);
      arow_[q] = rr;
      ag[q] = (((l & 3) ^ ((rr >> 1) & 3)) << 2);
      adst[q] = (wv * 32 + q * 16) * 16;
    } else {
      int rr = wv * 32 + q * 8 + (l >> 3);
      arow_[q] = rr;
      ag[q] = (((l & 7) ^ (rr & 7)) << 2);
      adst[q] = (wv * 32 + q * 8) * 32;
    }
  }
  // B gload: always 2 chunks of 16 rows (16-u32 rows)
  int brow[2], bg[2], bdst[2];
  #pragma unroll
  for (int q = 0; q < 2; q++) {
    int rr = wv * 32 + q * 16 + (l >> 2);
    brow[q] = rr;
    bg[q] = (((l & 3) ^ ((rr >> 1) & 3)) << 2);
    bdst[q] = (wv * 32 + q * 16) * 16;
  }
  const u32* Brow = Bp + (size_t)n0 * 512;
  const u32* Agr  = Agl + (size_t)m0 * ARS;

  f32x4 acc[4][4];
  #pragma unroll
  for (int i = 0; i < 4; i++)
    #pragma unroll
    for (int j = 0; j < 4; j++) { f32x4 z = {0.f, 0.f, 0.f, 0.f}; acc[i][j] = z; }

  // prologue: stage slab 0
  #pragma unroll
  for (int q = 0; q < 2; q++)
    gload16(Brow + (size_t)brow[q] * 512 + bg[q], &sB[0][bdst[q]]);
  #pragma unroll
  for (int q = 0; q < ANQ; q++)
    gload16(Agr + (size_t)arow_[q] * ARS + ag[q], &sA[0][adst[q]]);
  __syncthreads();

  #pragma unroll 1
  for (int it = 0; it < 32; ++it) {
    const int cur = it & 1, nxt = cur ^ 1;
    const bool pf = (it < 31);
    if (pf) {
      const int soA = (CFG == 1) ? ((it + 1) << 4) : ((it + 1) << 5);
      const int soB = (it + 1) << 4;
      #pragma unroll
      for (int q = 0; q < 2; q++)
        gload16(Brow + (size_t)brow[q] * 512 + soB + bg[q], &sB[nxt][bdst[q]]);
      #pragma unroll
      for (int q = 0; q < ANQ; q++)
        gload16(Agr + (size_t)arow_[q] * ARS + soA + ag[q], &sA[nxt][adst[q]]);
    }
    bf16x8 Ah[4], Al_[4], Bh[4];
    #pragma unroll
    for (int i = 0; i < 4; i++) {
      Ah[i] = *(const bf16x8*)&sA[cur][fAh[i]];
      Bh[i] = *(const bf16x8*)&sB[cur][fBh[i]];
      if (CFG == 2) Al_[i] = *(const bf16x8*)&sA[cur][fAl[i]];
    }
    #pragma unroll
    for (int i = 0; i < 4; i++)
      #pragma unroll
      for (int j = 0; j < 4; j++) {
        acc[i][j] = MFMA16(Ah[i], Bh[j], acc[i][j]);
        if (CFG == 2) acc[i][j] = MFMA16(Al_[i], Bh[j], acc[i][j]);
      }
    __syncthreads();
  }

  // epilogue: D row = lk*4 + reg, col = lr [m89 layout]; optional col stats
  float* Cf = (float*)Cptr;
  u32*   Cu = (u32*)Cptr;
  float st1[4], st2[4];
  #pragma unroll
  for (int j = 0; j < 4; j++) { st1[j] = 0.f; st2[j] = 0.f; }
  #pragma unroll
  for (int j = 0; j < 4; j++) {
    int ocol = n0 + wn + j * 16 + lr;
    float bj = bias[ocol];
    #pragma unroll
    for (int i = 0; i < 4; i++) {
      int orow = m0 + wm + i * 16 + lk * 4;
      #pragma unroll
      for (int reg = 0; reg < 4; reg++) {
        float v = acc[i][j][reg] + bj;
        if (STATS) { st1[j] += v; st2[j] = fmaf(v, v, st2[j]); }
        int row = orow + reg;
        if (OUT == 0) {
          Cf[(size_t)row * CC + ocol] = v;
        } else {
          float pv = __shfl_xor(v, 1);
          if (!(lr & 1)) {
            if (OUT == 1) {
              Cu[(size_t)row * 512 + (ocol >> 1)] = rne_pack(v, pv);
            } else {
              int slab = ocol >> 5, jj = (ocol & 31) >> 1;
              u32 ua = __float_as_uint(v), ub = __float_as_uint(pv);
              u32 hi = (ua >> 16) | (ub & 0xFFFF0000u);
              float la = v  - __uint_as_float(ua & 0xFFFF0000u);
              float lb = pv - __uint_as_float(ub & 0xFFFF0000u);
              u32 lo = (__float_as_uint(la) >> 16) |
                       (__float_as_uint(lb) & 0xFFFF0000u);
              u32* cp = Cu + (size_t)row * 1024 + slab * 32 + jj;
              cp[0]  = hi;
              cp[16] = lo;
            }
          }
        }
      }
    }
  }
  if (STATS) {
    float* srb = (float*)&sA[0][0];   // sA is dead after the K-loop
    #pragma unroll
    for (int j = 0; j < 4; j++) {
      st1[j] += __shfl_xor(st1[j], 16, 64);
      st1[j] += __shfl_xor(st1[j], 32, 64);
      st2[j] += __shfl_xor(st2[j], 16, 64);
      st2[j] += __shfl_xor(st2[j], 32, 64);
    }
    if (lk == 0) {
      #pragma unroll
      for (int j = 0; j < 4; j++) {
        srb[wv * 64 + j * 16 + lr]       = st1[j];
        srb[256 + wv * 64 + j * 16 + lr] = st2[j];
      }
    }
    __syncthreads();
    if (t < 128) {
      int ch = t >> 6, c6 = t & 63;
      float a1 = srb[ch * 64 + c6] + srb[(ch + 2) * 64 + c6];
      float a2 = srb[256 + ch * 64 + c6] + srb[256 + (ch + 2) * 64 + c6];
      float2 o = { a1, a2 };
      *(float2*)(partOut + ((size_t)mb * CC + n0 + t) * 2) = o;
    }
  }
}

// conv wrapper with grouped block swizzle (SWZ_G m-tiles x 8 n-tiles per group)
#define SWZ_G 64

template<int OUT, bool STATS>
__global__ __launch_bounds__(256, 2)
void k_mg(const u32* __restrict__ A, const u32* __restrict__ Bp,
          const float* __restrict__ bias, void* __restrict__ Cptr,
          int mtiles, float* __restrict__ partOut)
{
  int id = blockIdx.y * gridDim.x + blockIdx.x;
  int g = id / (SWZ_G * 8);
  int rem = id - g * (SWZ_G * 8);
  int gsz = mtiles - g * SWZ_G; if (gsz > SWZ_G) gsz = SWZ_G;
  int mt = g * SWZ_G + rem % gsz;
  int nt = rem / gsz;
  mg_body<1, OUT, STATS>(A, Bp, bias, Cptr, mt * 128, nt * 128, partOut, mt);
}

__global__ __launch_bounds__(256, 2)
void k_heads(const u32* __restrict__ ctxp, const u32* __restrict__ wplh,
             const float* __restrict__ lb, float* __restrict__ out)
{
  int p, w;
  head_entry(blockIdx.y, &p, &w);
  mg_body<2, 0, false>(ctxp + (size_t)p * BB * 1024,
                       wplh + (size_t)w * 524288,
                       lb + (size_t)w * CC,
                       out + (size_t)blockIdx.y * BB * CC,
                       (blockIdx.x >> 3) * 128, (blockIdx.x & 7) * 128,
                       nullptr, 0);
}

// ---------------------------------------------------------------- launch

extern "C" void kernel_launch(void* const* d_in, const int* in_sizes, int n_in,
                              void* d_out, int out_size, void* d_ws, size_t ws_size,
                              hipStream_t stream)
{
  const float* x   = (const float*)d_in[0];
  const float* bng = (const float*)d_in[1];
  const float* bnb = (const float*)d_in[2];
  const float* cw  = (const float*)d_in[3];
  const float* cb  = (const float*)d_in[4];
  const float* lw  = (const float*)d_in[5];
  const float* lb  = (const float*)d_in[6];
  float* out = (float*)d_out;

  const size_t W = ws_size / 4;           // 4-byte words
  const size_t SZ_WHI  = 3ull * 524288;   // conv weights, RNE hi-only
  const size_t SZ_WPL  = 12ull * 524288;  // head weights, RNE hi-only
  const size_t SZ_PS   = 6400ull * 512;   // pooled RNE hi-only (u32)
  const size_t SZ_CTXP = 6400ull * 1024;  // ctx trunc hi/lo gload (u32)
  const size_t SZ_XS   = 50176;
  const size_t SZ_SS   = 25ull * 1024;

  auto need = [&](int pc) -> size_t {
    return SZ_WHI + SZ_WPL
         + 2ull * pc * 2304 * 512           // bufS + bufO (u32)
         + SZ_PS + SZ_CTXP + 2 * SZ_XS + 2 * SZ_SS
         + (size_t)pc * 18 * 1024 * 2;
  };
  int PC;
  if      (W >= need(25)) PC = 25;
  else if (W >= need(5))  PC = 5;
  else                    PC = 1;

  u32*   whi    = (u32*)d_ws;
  u32*   wpl    = whi + SZ_WHI;
  u32*   bufS   = wpl + SZ_WPL;
  u32*   bufO   = bufS + (size_t)PC * 2304 * 512;
  u32*   pooledS= bufO + (size_t)PC * 2304 * 512;
  u32*   ctxp   = pooledS + SZ_PS;
  float* xs1    = (float*)(ctxp + SZ_CTXP);
  float* xs2    = xs1 + SZ_XS;
  float* ssc    = xs2 + SZ_XS;
  float* ssh    = ssc + SZ_SS;
  float* part   = ssh + SZ_SS;

  // weight pre-split: conv + heads, both RNE hi-only
  k_wsplit_rn<<<(int)(SZ_WHI / 256), 256, 0, stream>>>(cw, whi, (int)SZ_WHI);
  k_wsplit_rn<<<(int)(SZ_WPL / 256), 256, 0, stream>>>(lw, wpl, (int)SZ_WPL);
  k_xsums<<<196, 256, 0, stream>>>(x, xs1, xs2);
  k_stats1<<<dim3(25, 4), 256, 0, stream>>>(xs1, xs2, bng, bnb, ssc, ssh);

  for (int pbase = 0; pbase < NP; pbase += PC) {
    const int rows = PC * 2304;
    const int mtiles = PC * 18;
    const dim3 gconv(mtiles, 8);
    // A1: fused transpose + BN1 + relu + RNE -> bufS
    k_tsplit<<<dim3(256, 8), 256, 0, stream>>>(x, ssc, ssh, bufS, pbase, PC);
    // conv1: bufS -> bufO (bf16-pairs), col stats -> part
    k_mg<1, true><<<gconv, 256, 0, stream>>>(bufS, whi, cb, bufO, mtiles, part);
    k_statsfin<<<dim3(PC, 4), 256, 0, stream>>>(part, bng + CC, bnb + CC, ssc, ssh, pbase);
    // A2: BN2+relu+RNE from bufO -> bufS
    k_absplit<<<rows / 8, 256, 0, stream>>>(bufO, ssc, ssh, bufS, pbase);
    // conv2: bufS -> bufO (bf16-pairs), stats -> part
    k_mg<1, true><<<gconv, 256, 0, stream>>>(bufS, whi + 524288, cb + CC,
                                             bufO, mtiles, part);
    k_statsfin<<<dim3(PC, 4), 256, 0, stream>>>(part, bng + 2 * CC, bnb + 2 * CC, ssc, ssh, pbase);
    // BN3+relu+pool from bufO, RNE output -> pooledS slice
    k_pool<<<PC * 256, 256, 0, stream>>>(bufO, ssc, ssh, pooledS, pbase);
  }

  // conv3 over all pooled rows -> ctxp (trunc hi/lo gload layout, direct)
  k_mg<2, false><<<dim3(50, 8), 256, 0, stream>>>(pooledS, whi + 2 * 524288,
                                                  cb + 2 * CC, ctxp, 50, nullptr);
  // heads: A = ctxp (2-plane), B = head weights (RNE hi-only), 2 products
  k_heads<<<dim3(16, 120), 256, 0, stream>>>(ctxp, wpl, lb, out);
}

// Round 17
// 635.190 us; speedup vs baseline: 1.9103x; 1.0493x over previous
//
#include <hip/hip_runtime.h>
#include <hip/hip_bf16.h>
#include <stdint.h>

#define BB 256
#define CC 1024
#define NP 25
#define EPS 1e-5f

typedef __attribute__((ext_vector_type(8))) short bf16x8;
typedef __attribute__((ext_vector_type(4))) float f32x4;
typedef unsigned int u32;

#define MFMA16(A, B, C) __builtin_amdgcn_mfma_f32_16x16x32_bf16(A, B, C, 0, 0, 0)

// async global->LDS, 16B per lane; LDS dest = wave-uniform base + lane*16
__device__ __forceinline__ void gload16(const u32* g, u32* l)
{
  __builtin_amdgcn_global_load_lds(
      (const __attribute__((address_space(1))) u32*)g,
      (__attribute__((address_space(3))) u32*)l, 16, 0, 0);
}

// ---------------------------------------------------------------- utils

__device__ __forceinline__ void head_entry(int j, int* pp, int* ww)
{
  int cnt = 0;
  for (int y1 = 0; y1 < 5; y1++)
    for (int x1 = 0; x1 < 5; x1++) {
      int p = y1 * 5 + x1;
      int y2 = y1 + 2, x2 = x1 + 2;
      if (y2 == 2 || y2 == 3)
        for (int s = 0; s < 3; s++) { if (y2 + s + 1 > 6) break; if (cnt == j) { *pp = p; *ww = 0 + s; return; } cnt++; }
      if (y1 == 3 || y1 == 4)
        for (int s = 0; s < 3; s++) { if (y1 - (s + 1) < 0) break; if (cnt == j) { *pp = p; *ww = 3 + s; return; } cnt++; }
      if (x2 == 2 || x2 == 3)
        for (int s = 0; s < 3; s++) { if (x2 + s + 1 > 6) break; if (cnt == j) { *pp = p; *ww = 6 + s; return; } cnt++; }
      if (x1 == 3 || x1 == 4)
        for (int s = 0; s < 3; s++) { if (x1 - (s + 1) < 0) break; if (cnt == j) { *pp = p; *ww = 9 + s; return; } cnt++; }
    }
}

// round-to-nearest-even bf16 (keep high 16 bits)
__device__ __forceinline__ u32 rne_hi(u32 x)
{
  return (x + 0x7FFFu + ((x >> 16) & 1u)) & 0xFFFF0000u;
}

// pack two floats as RNE bf16 pair into one u32 (a -> low, b -> high)
__device__ __forceinline__ u32 rne_pack(float a, float b)
{
  return (rne_hi(__float_as_uint(a)) >> 16) | rne_hi(__float_as_uint(b));
}

__device__ __forceinline__ float bflo(u32 u) { return __uint_as_float(u << 16); }
__device__ __forceinline__ float bfhi(u32 u) { return __uint_as_float(u & 0xFFFF0000u); }

// ------------------------------------------------- layer-1 stats from x

__global__ void k_xsums(const float* __restrict__ x, float* __restrict__ xs1,
                        float* __restrict__ xs2)
{
  int pos = blockIdx.x * 256 + threadIdx.x;   // < 50176
  float s1 = 0.f, s2 = 0.f;
  for (int b = 0; b < BB; b++) {
    float v = x[(size_t)b * 50176 + pos];
    s1 += v; s2 = fmaf(v, v, s2);
  }
  xs1[pos] = s1; xs2[pos] = s2;
}

__global__ void k_stats1(const float* __restrict__ xs1, const float* __restrict__ xs2,
                         const float* __restrict__ gam, const float* __restrict__ bet,
                         float* __restrict__ ssc, float* __restrict__ ssh)
{
  int p = blockIdx.x;
  int c = blockIdx.y * 256 + threadIdx.x;
  int y1 = p / 5, x1 = p % 5;
  float s1 = 0.f, s2 = 0.f;
  for (int dy = 0; dy < 3; dy++)
    for (int dx = 0; dx < 3; dx++) {
      int pos = c * 49 + (y1 + dy) * 7 + (x1 + dx);
      s1 += xs1[pos]; s2 += xs2[pos];
    }
  const float inv = 1.0f / 2304.0f;
  float mean = s1 * inv;
  float var  = s2 * inv - mean * mean;
  float rs   = rsqrtf(var + EPS);
  float sc   = rs * gam[c];
  ssc[(size_t)p * CC + c] = sc;
  ssh[(size_t)p * CC + c] = bet[c] - mean * sc;
}

// ---- fused transpose + BN1 affine + relu + RNE -> bufS (512-u32 rows)

__global__ void k_tsplit(const float* __restrict__ x,
                         const float* __restrict__ ssc, const float* __restrict__ ssh,
                         u32* __restrict__ bufS, int pbase, int pcount)
{
  __shared__ float tile[128][51];
  int b = blockIdx.x, cg = blockIdx.y;
  const float* src = x + (size_t)b * 50176 + (size_t)cg * 128 * 49;
  for (int idx = threadIdx.x; idx < 6272; idx += 256)
    tile[idx / 49][idx % 49] = src[idx];
  __syncthreads();
  const int t = threadIdx.x;
  const int u = t & 63;
  const int segs = pcount * 9;
  for (int sg = t >> 6; sg < segs; sg += 4) {
    int pl = sg / 9, yx = sg - pl * 9;
    int p = pbase + pl;
    int pos = (p / 5 + yx / 3) * 7 + (p % 5) + (yx % 3);
    int c0 = cg * 128 + u * 2;
    float2 sc = *(const float2*)(ssc + (size_t)p * CC + c0);
    float2 sh = *(const float2*)(ssh + (size_t)p * CC + c0);
    float v0 = fmaxf(fmaf(tile[u * 2][pos],     sc.x, sh.x), 0.f);
    float v1 = fmaxf(fmaf(tile[u * 2 + 1][pos], sc.y, sh.y), 0.f);
    bufS[((size_t)pl * 2304 + b * 9 + yx) * 512 + cg * 64 + u] = rne_pack(v0, v1);
  }
}

// ---------- weights: RNE hi-only layout (512-u32 rows, slab = 16 u32)

__global__ void k_wsplit_rn(const float* __restrict__ w, u32* __restrict__ dst, int total)
{
  int g = blockIdx.x * 256 + threadIdx.x;
  if (g >= total) return;
  int row = g >> 9;
  int idx = g & 511;
  const float* src = w + ((size_t)row << 10) + 2 * idx;
  dst[g] = rne_pack(src[0], src[1]);
}

// ------------- conv2-A: BN2 affine + relu + RNE (bf16-pair src -> bufS)

__global__ void k_absplit(const u32* __restrict__ src,
                          const float* __restrict__ ssc, const float* __restrict__ ssh,
                          u32* __restrict__ dst, int pbase)
{
  int r = blockIdx.x * 8 + (threadIdx.x >> 5);   // local row
  int slab = threadIdx.x & 31;
  int pg = pbase + r / 2304;
  const u32* su = src + (size_t)r * 512 + slab * 16;
  const float* scp = ssc + (size_t)pg * CC + slab * 32;
  const float* shp = ssh + (size_t)pg * CC + slab * 32;
  u32 hi[16];
  #pragma unroll
  for (int j = 0; j < 8; j++) {
    u32 p0 = su[2 * j], p1 = su[2 * j + 1];
    float4 f = { bflo(p0), bfhi(p0), bflo(p1), bfhi(p1) };
    float4 s = *(const float4*)(scp + 4 * j);
    float4 h = *(const float4*)(shp + 4 * j);
    f.x = fmaxf(fmaf(f.x, s.x, h.x), 0.f);
    f.y = fmaxf(fmaf(f.y, s.y, h.y), 0.f);
    f.z = fmaxf(fmaf(f.z, s.z, h.z), 0.f);
    f.w = fmaxf(fmaf(f.w, s.w, h.w), 0.f);
    hi[2 * j]     = rne_pack(f.x, f.y);
    hi[2 * j + 1] = rne_pack(f.z, f.w);
  }
  u32* op = dst + (size_t)r * 512 + slab * 16;
  *(uint4*)(op + 0)  = make_uint4(hi[0], hi[1], hi[2], hi[3]);
  *(uint4*)(op + 4)  = make_uint4(hi[4], hi[5], hi[6], hi[7]);
  *(uint4*)(op + 8)  = make_uint4(hi[8], hi[9], hi[10], hi[11]);
  *(uint4*)(op + 12) = make_uint4(hi[12], hi[13], hi[14], hi[15]);
}

// ------------------- finalize BN stats from per-mblock partials (18/patch)

__global__ void k_statsfin(const float* __restrict__ part, const float* __restrict__ gam,
                           const float* __restrict__ bet, float* __restrict__ ssc,
                           float* __restrict__ ssh, int pbase)
{
  int pl = blockIdx.x;
  int c  = blockIdx.y * 256 + threadIdx.x;
  float s1 = 0.f, s2 = 0.f;
  for (int mb = 0; mb < 18; mb++) {
    const float* pp = part + ((size_t)(pl * 18 + mb) * CC + c) * 2;
    s1 += pp[0]; s2 += pp[1];
  }
  const float inv = 1.0f / 2304.0f;
  float mean = s1 * inv;
  float var  = s2 * inv - mean * mean;
  float rs   = rsqrtf(var + EPS);
  float sc   = rs * gam[c];
  int pg = pbase + pl;
  ssc[(size_t)pg * CC + c] = sc;
  ssh[(size_t)pg * CC + c] = bet[c] - mean * sc;
}

// ---- BN3 affine+relu + 3x3 mean pooling; input bf16-pairs, output RNE hi-only

__global__ void k_pool(const u32* __restrict__ h, const float* __restrict__ ssc,
                       const float* __restrict__ ssh, u32* __restrict__ apool, int pbase)
{
  int row = blockIdx.x;                 // local: pl*256 + b
  int pl = row >> 8;
  int pg = pbase + pl;
  int c = threadIdx.x * 4;
  float4 sc = *(const float4*)(ssc + (size_t)pg * CC + c);
  float4 sh = *(const float4*)(ssh + (size_t)pg * CC + c);
  const u32* hp = h + (size_t)row * 9 * 512 + (c >> 1);
  float4 s = {0.f, 0.f, 0.f, 0.f};
  #pragma unroll
  for (int yx = 0; yx < 9; yx++) {
    uint2 pp = *(const uint2*)(hp + (size_t)yx * 512);
    float4 v = { bflo(pp.x), bfhi(pp.x), bflo(pp.y), bfhi(pp.y) };
    s.x += fmaxf(fmaf(v.x, sc.x, sh.x), 0.f);
    s.y += fmaxf(fmaf(v.y, sc.y, sh.y), 0.f);
    s.z += fmaxf(fmaf(v.z, sc.z, sh.z), 0.f);
    s.w += fmaxf(fmaf(v.w, sc.w, sh.w), 0.f);
  }
  const float inv9 = 1.0f / 9.0f;
  uint2 o = { rne_pack(s.x * inv9, s.y * inv9), rne_pack(s.z * inv9, s.w * inv9) };
  u32* op = apool + ((size_t)(pbase * 256) + row) * 512 + (c >> 1);
  *(uint2*)op = o;
}

// ------------------------------------------------------------ MFMA GEMM core
// C[m][n] = sum_k A[m][k] * B[n][k] + bias[n]; A and B both RNE hi-only bf16
// (512-u32 rows, granule g^((row>>1)&3), 2-way max), staged via global_load_lds.
// 1 MFMA product per frag-pair. Used by convs AND heads (A=ctx RNE).
// OUT=0 fp32 rows; OUT=1 RNE bf16-pair rows (512-u32, lane-pair shfl pack).
// STATS: per-block column sum/sumsq -> partOut[mb][col][2].
// Stats scratch aliases sA (dead after the K-loop) -> LDS = 32 KB.

template<int OUT, bool STATS>
__device__ __forceinline__ void mg_body(
    const u32* __restrict__ Agl, const u32* __restrict__ Bp,
    const float* __restrict__ bias, void* __restrict__ Cptr,
    int m0, int n0, float* __restrict__ partOut, int mb)
{
  __shared__ u32 sA[2][128 * 16];
  __shared__ u32 sB[2][128 * 16];

  const int t = threadIdx.x;
  const int l = t & 63, wv = t >> 6;
  const int lr = l & 15, lk = l >> 4;
  const int wm = (wv >> 1) * 64, wn = (wv & 1) * 64;

  // fragment read offsets (u32) with granule XOR swizzle
  int fAh[4], fBh[4];
  #pragma unroll
  for (int i = 0; i < 4; i++) {
    int Ra = wm + i * 16 + lr;
    int Rb = wn + i * 16 + lr;
    fAh[i] = Ra * 16 + ((lk ^ ((Ra >> 1) & 3)) << 2);
    fBh[i] = Rb * 16 + ((lk ^ ((Rb >> 1) & 3)) << 2);
  }

  // gload addressing: 2 chunks of 16 rows (16-u32 rows) per operand
  int grow[2], gg[2], gdst[2];
  #pragma unroll
  for (int q = 0; q < 2; q++) {
    int rr = wv * 32 + q * 16 + (l >> 2);
    grow[q] = rr;
    gg[q] = (((l & 3) ^ ((rr >> 1) & 3)) << 2);
    gdst[q] = (wv * 32 + q * 16) * 16;
  }
  const u32* Brow = Bp + (size_t)n0 * 512;
  const u32* Agr  = Agl + (size_t)m0 * 512;

  f32x4 acc[4][4];
  #pragma unroll
  for (int i = 0; i < 4; i++)
    #pragma unroll
    for (int j = 0; j < 4; j++) { f32x4 z = {0.f, 0.f, 0.f, 0.f}; acc[i][j] = z; }

  // prologue: stage slab 0
  #pragma unroll
  for (int q = 0; q < 2; q++) {
    gload16(Brow + (size_t)grow[q] * 512 + gg[q], &sB[0][gdst[q]]);
    gload16(Agr + (size_t)grow[q] * 512 + gg[q], &sA[0][gdst[q]]);
  }
  __syncthreads();

  #pragma unroll 1
  for (int it = 0; it < 32; ++it) {
    const int cur = it & 1, nxt = cur ^ 1;
    const bool pf = (it < 31);
    if (pf) {
      const int so = (it + 1) << 4;
      #pragma unroll
      for (int q = 0; q < 2; q++) {
        gload16(Brow + (size_t)grow[q] * 512 + so + gg[q], &sB[nxt][gdst[q]]);
        gload16(Agr + (size_t)grow[q] * 512 + so + gg[q], &sA[nxt][gdst[q]]);
      }
    }
    bf16x8 Ah[4], Bh[4];
    #pragma unroll
    for (int i = 0; i < 4; i++) {
      Ah[i] = *(const bf16x8*)&sA[cur][fAh[i]];
      Bh[i] = *(const bf16x8*)&sB[cur][fBh[i]];
    }
    #pragma unroll
    for (int i = 0; i < 4; i++)
      #pragma unroll
      for (int j = 0; j < 4; j++)
        acc[i][j] = MFMA16(Ah[i], Bh[j], acc[i][j]);
    __syncthreads();
  }

  // epilogue: D row = lk*4 + reg, col = lr [m89 layout]; optional col stats
  float* Cf = (float*)Cptr;
  u32*   Cu = (u32*)Cptr;
  float st1[4], st2[4];
  #pragma unroll
  for (int j = 0; j < 4; j++) { st1[j] = 0.f; st2[j] = 0.f; }
  #pragma unroll
  for (int j = 0; j < 4; j++) {
    int ocol = n0 + wn + j * 16 + lr;
    float bj = bias[ocol];
    #pragma unroll
    for (int i = 0; i < 4; i++) {
      int orow = m0 + wm + i * 16 + lk * 4;
      #pragma unroll
      for (int reg = 0; reg < 4; reg++) {
        float v = acc[i][j][reg] + bj;
        if (STATS) { st1[j] += v; st2[j] = fmaf(v, v, st2[j]); }
        int row = orow + reg;
        if (OUT == 0) {
          Cf[(size_t)row * CC + ocol] = v;
        } else {
          float pv = __shfl_xor(v, 1);
          if (!(lr & 1))
            Cu[(size_t)row * 512 + (ocol >> 1)] = rne_pack(v, pv);
        }
      }
    }
  }
  if (STATS) {
    float* srb = (float*)&sA[0][0];   // sA is dead after the K-loop
    #pragma unroll
    for (int j = 0; j < 4; j++) {
      st1[j] += __shfl_xor(st1[j], 16, 64);
      st1[j] += __shfl_xor(st1[j], 32, 64);
      st2[j] += __shfl_xor(st2[j], 16, 64);
      st2[j] += __shfl_xor(st2[j], 32, 64);
    }
    if (lk == 0) {
      #pragma unroll
      for (int j = 0; j < 4; j++) {
        srb[wv * 64 + j * 16 + lr]       = st1[j];
        srb[256 + wv * 64 + j * 16 + lr] = st2[j];
      }
    }
    __syncthreads();
    if (t < 128) {
      int ch = t >> 6, c6 = t & 63;
      float a1 = srb[ch * 64 + c6] + srb[(ch + 2) * 64 + c6];
      float a2 = srb[256 + ch * 64 + c6] + srb[256 + (ch + 2) * 64 + c6];
      float2 o = { a1, a2 };
      *(float2*)(partOut + ((size_t)mb * CC + n0 + t) * 2) = o;
    }
  }
}

// conv wrapper with grouped block swizzle (SWZ_G m-tiles x 8 n-tiles per group)
#define SWZ_G 64

template<int OUT, bool STATS>
__global__ __launch_bounds__(256, 2)
void k_mg(const u32* __restrict__ A, const u32* __restrict__ Bp,
          const float* __restrict__ bias, void* __restrict__ Cptr,
          int mtiles, float* __restrict__ partOut)
{
  int id = blockIdx.y * gridDim.x + blockIdx.x;
  int g = id / (SWZ_G * 8);
  int rem = id - g * (SWZ_G * 8);
  int gsz = mtiles - g * SWZ_G; if (gsz > SWZ_G) gsz = SWZ_G;
  int mt = g * SWZ_G + rem % gsz;
  int nt = rem / gsz;
  mg_body<OUT, STATS>(A, Bp, bias, Cptr, mt * 128, nt * 128, partOut, mt);
}

__global__ __launch_bounds__(256, 2)
void k_heads(const u32* __restrict__ ctxp, const u32* __restrict__ wplh,
             const float* __restrict__ lb, float* __restrict__ out)
{
  int p, w;
  head_entry(blockIdx.y, &p, &w);
  mg_body<0, false>(ctxp + (size_t)p * BB * 512,
                    wplh + (size_t)w * 524288,
                    lb + (size_t)w * CC,
                    out + (size_t)blockIdx.y * BB * CC,
                    (blockIdx.x >> 3) * 128, (blockIdx.x & 7) * 128,
                    nullptr, 0);
}

// ---------------------------------------------------------------- launch

extern "C" void kernel_launch(void* const* d_in, const int* in_sizes, int n_in,
                              void* d_out, int out_size, void* d_ws, size_t ws_size,
                              hipStream_t stream)
{
  const float* x   = (const float*)d_in[0];
  const float* bng = (const float*)d_in[1];
  const float* bnb = (const float*)d_in[2];
  const float* cw  = (const float*)d_in[3];
  const float* cb  = (const float*)d_in[4];
  const float* lw  = (const float*)d_in[5];
  const float* lb  = (const float*)d_in[6];
  float* out = (float*)d_out;

  const size_t W = ws_size / 4;           // 4-byte words
  const size_t SZ_WHI  = 3ull * 524288;   // conv weights, RNE hi-only
  const size_t SZ_WPL  = 12ull * 524288;  // head weights, RNE hi-only
  const size_t SZ_PS   = 6400ull * 512;   // pooled RNE hi-only (u32)
  const size_t SZ_CTXP = 6400ull * 512;   // ctx RNE hi-only (u32)
  const size_t SZ_XS   = 50176;
  const size_t SZ_SS   = 25ull * 1024;

  auto need = [&](int pc) -> size_t {
    return SZ_WHI + SZ_WPL
         + 2ull * pc * 2304 * 512           // bufS + bufO (u32)
         + SZ_PS + SZ_CTXP + 2 * SZ_XS + 2 * SZ_SS
         + (size_t)pc * 18 * 1024 * 2;
  };
  int PC;
  if      (W >= need(25)) PC = 25;
  else if (W >= need(5))  PC = 5;
  else                    PC = 1;

  u32*   whi    = (u32*)d_ws;
  u32*   wpl    = whi + SZ_WHI;
  u32*   bufS   = wpl + SZ_WPL;
  u32*   bufO   = bufS + (size_t)PC * 2304 * 512;
  u32*   pooledS= bufO + (size_t)PC * 2304 * 512;
  u32*   ctxp   = pooledS + SZ_PS;
  float* xs1    = (float*)(ctxp + SZ_CTXP);
  float* xs2    = xs1 + SZ_XS;
  float* ssc    = xs2 + SZ_XS;
  float* ssh    = ssc + SZ_SS;
  float* part   = ssh + SZ_SS;

  // weight pre-split: conv + heads, both RNE hi-only
  k_wsplit_rn<<<(int)(SZ_WHI / 256), 256, 0, stream>>>(cw, whi, (int)SZ_WHI);
  k_wsplit_rn<<<(int)(SZ_WPL / 256), 256, 0, stream>>>(lw, wpl, (int)SZ_WPL);
  k_xsums<<<196, 256, 0, stream>>>(x, xs1, xs2);
  k_stats1<<<dim3(25, 4), 256, 0, stream>>>(xs1, xs2, bng, bnb, ssc, ssh);

  for (int pbase = 0; pbase < NP; pbase += PC) {
    const int rows = PC * 2304;
    const int mtiles = PC * 18;
    const dim3 gconv(mtiles, 8);
    // A1: fused transpose + BN1 + relu + RNE -> bufS
    k_tsplit<<<dim3(256, 8), 256, 0, stream>>>(x, ssc, ssh, bufS, pbase, PC);
    // conv1: bufS -> bufO (bf16-pairs), col stats -> part
    k_mg<1, true><<<gconv, 256, 0, stream>>>(bufS, whi, cb, bufO, mtiles, part);
    k_statsfin<<<dim3(PC, 4), 256, 0, stream>>>(part, bng + CC, bnb + CC, ssc, ssh, pbase);
    // A2: BN2+relu+RNE from bufO -> bufS
    k_absplit<<<rows / 8, 256, 0, stream>>>(bufO, ssc, ssh, bufS, pbase);
    // conv2: bufS -> bufO (bf16-pairs), stats -> part
    k_mg<1, true><<<gconv, 256, 0, stream>>>(bufS, whi + 524288, cb + CC,
                                             bufO, mtiles, part);
    k_statsfin<<<dim3(PC, 4), 256, 0, stream>>>(part, bng + 2 * CC, bnb + 2 * CC, ssc, ssh, pbase);
    // BN3+relu+pool from bufO, RNE output -> pooledS slice
    k_pool<<<PC * 256, 256, 0, stream>>>(bufO, ssc, ssh, pooledS, pbase);
  }

  // conv3 over all pooled rows -> ctxp (RNE bf16-pairs, direct)
  k_mg<1, false><<<dim3(50, 8), 256, 0, stream>>>(pooledS, whi + 2 * 524288,
                                                  cb + 2 * CC, ctxp, 50, nullptr);
  // heads: A = ctxp (RNE), B = head weights (RNE), 1 product
  k_heads<<<dim3(16, 120), 256, 0, stream>>>(ctxp, wpl, lb, out);
}